// Round 7
// baseline (3927.203 us; speedup 1.0000x reference)
//
#include <hip/hip_runtime.h>
#include <math.h>

typedef unsigned short ushortT;
typedef __attribute__((ext_vector_type(4))) float f32x4;
typedef __attribute__((ext_vector_type(4))) unsigned int u32x4;
typedef __attribute__((ext_vector_type(4))) unsigned short u16x4;
typedef __attribute__((ext_vector_type(4))) int i32x4;
typedef __attribute__((ext_vector_type(8))) __bf16 bf16x8;

namespace {
constexpr int S = 256;
constexpr int H = 768;
constexpr int NLAY = 12;
constexpr int NHD = 12;
constexpr int FF = 3072;
constexpr int LBL = 9;
constexpr int DH = 64;
constexpr int BATCH = 32;
constexpr int TOKENS = BATCH * S;      // 8192
constexpr int QKVN = 3 * H;            // 2304
// softmax scale folded into exponent: p = exp2(C2*(s_raw - m_raw)), C2 = 0.125*log2(e)
constexpr float C2 = 0.18033688011112042f;

// workspace layout (float-slot units)
constexpr size_t H_OFF   = 0;                          // h f32 [8192*768]
constexpr size_t HB_OFF  = H_OFF + (size_t)TOKENS*H;   // h bf16 (half slots)
constexpr size_t QB_OFF  = HB_OFF + (size_t)TOKENS*H/2;  // q / ctx / ff2out bf16
constexpr size_t KB_OFF  = QB_OFF + (size_t)TOKENS*H/2;  // k / attn-out bf16
constexpr size_t VT_OFF  = KB_OFF + (size_t)TOKENS*H/2;  // v^T bf16 [B*NH*DH][S]
constexpr size_t BIG_OFF = VT_OFF + (size_t)TOKENS*H/2;  // ff1 bf16 [8192][3072]
constexpr size_t WTQ_OFF = BIG_OFF + (size_t)TOKENS*FF/2;  // Wq^T,Wk^T,Wv^T contiguous
constexpr size_t WTO_OFF = WTQ_OFF + 3*(size_t)H*H/2;
constexpr size_t WT1_OFF = WTO_OFF + (size_t)H*H/2;      // W1^T [3072][768]
constexpr size_t WT2_OFF = WT1_OFF + (size_t)H*FF/2;     // W2^T [768][3072]
constexpr size_t EM_OFF  = WT2_OFF + (size_t)H*FF/2;
constexpr size_t PART_OFF= EM_OFF + (size_t)TOKENS*LBL;
constexpr size_t BQKV_OFF= PART_OFF + 64;                // packed qkv bias [12][2304]
constexpr size_t WS_FLOATS = BQKV_OFF + (size_t)NLAY*QKVN;
}

__device__ __forceinline__ ushortT f2bf(float x) {
    unsigned u = __builtin_bit_cast(unsigned, x);
    u += 0x7fffu + ((u >> 16) & 1u);
    return (ushortT)(u >> 16);
}
__device__ __forceinline__ float bf2f(ushortT h) {
    unsigned u = ((unsigned)h) << 16;
    return __builtin_bit_cast(float, u);
}

__device__ __forceinline__ float exp2i(float x) {
    float r; asm("v_exp_f32 %0, %1" : "=v"(r) : "v"(x)); return r;
}
__device__ __forceinline__ float log2i(float x) {
    float r; asm("v_log_f32 %0, %1" : "=v"(r) : "v"(x)); return r;
}

// tanh-gelu in sigmoid form: 0.5x(1+tanh(u)) == x * sigmoid(2u) == x/(1+exp2(-2u*log2e))
__device__ __forceinline__ float gelu_tanh(float x) {
    float u = 0.7978845608028654f * (x + 0.044715f * x * x * x);
    float t = exp2i(-2.8853900817779268f * u);
    return x / (1.0f + t);
}

__device__ __forceinline__ f32x4 mfma16(u32x4 a, u32x4 b, f32x4 c) {
    return __builtin_amdgcn_mfma_f32_16x16x32_bf16(
        __builtin_bit_cast(bf16x8, a), __builtin_bit_cast(bf16x8, b), c, 0, 0, 0);
}

__device__ __forceinline__ void gload_lds16(const ushortT* g, ushortT* l) {
    __builtin_amdgcn_global_load_lds(
        (const __attribute__((address_space(1))) unsigned int*)g,
        (__attribute__((address_space(3))) unsigned int*)l,
        16, 0, 0);
}

// ---------------- bf16 MFMA GEMM, double-buffered 2-phase (128^2) ----------------
// C[m,n] = epi( sum_k A[m,k]*Bt[n,k] + bias[n] )
// MODE: 0 = bf16 + bias | 1 = bf16 + bias + gelu | 5 = fused-QKV routing
//       (Cv = q base; k at +TOKENS*H; v^T per head at +2*TOKENS*H)
template<int WM, int WN, int MODE>
__global__ __launch_bounds__(256) void gemm_mfma(
    const ushortT* __restrict__ A, int lda, long long sAo, long long sAi,
    const ushortT* __restrict__ Bt, int ldb, long long sBo, long long sBi,
    const float* __restrict__ bias,
    void* __restrict__ Cv, int ldc, long long sCo, long long sCi,
    int K, int innerN)
{
    constexpr int BM = WM * 64, BN = WN * 64;
    __shared__ __align__(16) ushortT As[2][BM * 32];
    __shared__ __align__(16) ushortT Bs[2][BN * 32];
    const int tid = threadIdx.x;
    const int wave = tid >> 6, lane = tid & 63;
    const int ob = blockIdx.z / innerN, ib = blockIdx.z - ob * innerN;
    const int bm = blockIdx.y * BM, bn = blockIdx.x * BN;
    const ushortT* Ab = A + ob * sAo + ib * sAi + (size_t)bm * lda;
    const ushortT* Bb = Bt + ob * sBo + ib * sBi + (size_t)bn * ldb;
    const int wm = wave / WN, wn = wave - wm * WN;

    const int lrow = lane >> 2;
    const int lk16 = (lane & 3) * 8;
    const int rl = lane & 15;
    const int kg = (lane >> 4) * 8;

    f32x4 acc[4][4];
#pragma unroll
    for (int i = 0; i < 4; ++i)
#pragma unroll
        for (int j = 0; j < 4; ++j) acc[i][j] = (f32x4){0.f, 0.f, 0.f, 0.f};

    auto stage = [&](int buf, int k0) {
#pragma unroll
        for (int j = 0; j < WM; ++j) {
            int chunk = j * 4 + wave;
            gload_lds16(Ab + (size_t)(chunk * 16 + lrow) * lda + k0 + lk16,
                        &As[buf][chunk * 512]);
        }
#pragma unroll
        for (int j = 0; j < WN; ++j) {
            int chunk = j * 4 + wave;
            gload_lds16(Bb + (size_t)(chunk * 16 + lrow) * ldb + k0 + lk16,
                        &Bs[buf][chunk * 512]);
        }
    };

    stage(0, 0);
    __syncthreads();
    const int nt = K >> 5;
    int cur = 0;
    for (int t = 0; t < nt; ++t) {
        if (t + 1 < nt) stage(cur ^ 1, (t + 1) << 5);
        u32x4 a[4], b[4];
#pragma unroll
        for (int mf = 0; mf < 4; ++mf)
            a[mf] = *(const u32x4*)&As[cur][(wm * 64 + mf * 16 + rl) * 32 + kg];
#pragma unroll
        for (int nf = 0; nf < 4; ++nf)
            b[nf] = *(const u32x4*)&Bs[cur][(wn * 64 + nf * 16 + rl) * 32 + kg];
#pragma unroll
        for (int mf = 0; mf < 4; ++mf)
#pragma unroll
            for (int nf = 0; nf < 4; ++nf)
                acc[mf][nf] = mfma16(a[mf], b[nf], acc[mf][nf]);
        __syncthreads();
        cur ^= 1;
    }

    ushortT* Ch = (ushortT*)Cv + ob * sCo + ib * sCi;
#pragma unroll
    for (int nf = 0; nf < 4; ++nf) {
        int gn = bn + wn * 64 + nf * 16 + rl;
        float bv = bias[gn];
#pragma unroll
        for (int mf = 0; mf < 4; ++mf) {
            int gm = bm + wm * 64 + mf * 16 + ((lane >> 4) << 2);
            if constexpr (MODE == 5) {
                const int region = gn / H;          // 0=q,1=k,2=v
                const int col = gn - region * H;
                if (region < 2) {
                    ushortT* o = (ushortT*)Cv + (size_t)region * TOKENS * H;
#pragma unroll
                    for (int r = 0; r < 4; ++r)
                        o[(size_t)(gm + r) * H + col] = f2bf(acc[mf][nf][r] + bv);
                } else {
                    u16x4 o;
#pragma unroll
                    for (int r = 0; r < 4; ++r) o[r] = f2bf(acc[mf][nf][r] + bv);
                    const int b_ = gm >> 8, s0 = gm & 255;
                    const int h_ = col >> 6, dh = col & 63;
                    *(u16x4*)((ushortT*)Cv + 2 * (size_t)TOKENS * H +
                              (((size_t)(b_ * NHD + h_) * DH + dh) << 8) + s0) = o;
                }
            } else {
#pragma unroll
                for (int r = 0; r < 4; ++r) {
                    float x = acc[mf][nf][r] + bv;
                    if constexpr (MODE == 1) x = gelu_tanh(x);
                    Ch[(size_t)(gm + r) * ldc + gn] = f2bf(x);
                }
            }
        }
    }
}

// =====================================================================
// Fused flash attention, one block per (b,h), 4 waves (one per 64 q-rows).
// K[256][64] and V^T[64][256] staged in LDS via gload_lds16 with XOR
// swizzle (16B-chunk ^ row&7) pre-applied on the GLOBAL source (both-sides
// rule); P[64][64] per wave in swizzled LDS. Online softmax in base-2 with
// the 1/8 scale folded into the exponent constant; mask bias in raw-score
// domain (-8e9 = -1e9/0.125). No barriers after the initial staging sync.
// =====================================================================
__global__ __launch_bounds__(256, 1) void attn_fused_k(
    const ushortT* qbuf,                 // q rows [B*S][768] (also output!)
    const ushortT* __restrict__ kbuf,    // k rows [B*S][768]
    const ushortT* __restrict__ vtb,     // [B*NH][64][256]
    const int* __restrict__ mask,
    ushortT* outp)                       // = qbuf (same head cols only)
{
    __shared__ __align__(16) ushortT Klds[256 * 64];   // 32 KB
    __shared__ __align__(16) ushortT Vlds[64 * 256];   // 32 KB
    __shared__ __align__(16) ushortT Plds[4 * 64 * 64];// 32 KB (8 KB/wave)
    __shared__ float mlds[S];

    const int tid = threadIdx.x;
    const int wave = tid >> 6, lane = tid & 63;
    const int cl = lane & 15, rg = lane >> 4;   // col-in-frag, row-group
    const int kg = rg;                          // k-subgroup 0..3
    const int bb = blockIdx.x / NHD, hh = blockIdx.x - bb * NHD;

    // ---- stage K (8 rounds x 4KB): row s = r*32 + tid>>3, chunk = tid&7 ----
#pragma unroll
    for (int r = 0; r < 8; ++r)
        gload_lds16(kbuf + (size_t)(bb * 256 + r * 32 + (tid >> 3)) * H + hh * 64
                        + (((tid & 7) ^ ((tid >> 3) & 7)) << 3),
                    Klds + r * 2048 + tid * 8);
    // ---- stage V^T (8 rounds): row dh = r*8 + tid>>5, chunk = tid&31 ----
    const ushortT* vbase = vtb + (size_t)(bb * NHD + hh) * DH * S;
#pragma unroll
    for (int r = 0; r < 8; ++r)
        gload_lds16(vbase + (size_t)(r * 8 + (tid >> 5)) * S
                          + (((tid & 31) ^ ((tid >> 5) & 7)) << 3),
                    Vlds + r * 2048 + tid * 8);
    mlds[tid] = mask[bb * 256 + tid] ? 0.f : -8e9f;

    // ---- Q into registers (A-frags; row = cl, k-elems kg*8) ----
    u32x4 qreg[4][2];
#pragma unroll
    for (int mf = 0; mf < 4; ++mf)
#pragma unroll
        for (int ks = 0; ks < 2; ++ks)
            qreg[mf][ks] = *(const u32x4*)(qbuf +
                (size_t)(bb * 256 + wave * 64 + mf * 16 + cl) * H +
                hh * 64 + ks * 32 + kg * 8);

    __syncthreads();   // drains vmcnt (gload_lds + q loads) + barrier

    float mbias[16];
#pragma unroll
    for (int i = 0; i < 16; ++i) mbias[i] = mlds[i * 16 + cl];

    f32x4 accO[4][4];
    float mrow[4][4], lrowv[4][4];
#pragma unroll
    for (int mf = 0; mf < 4; ++mf) {
#pragma unroll
        for (int no = 0; no < 4; ++no) accO[mf][no] = (f32x4){0.f, 0.f, 0.f, 0.f};
#pragma unroll
        for (int r = 0; r < 4; ++r) { mrow[mf][r] = -1e30f; lrowv[mf][r] = 0.f; }
    }

#pragma unroll
    for (int c = 0; c < 4; ++c) {
        // ---- QK^T chunk: scores s[m][c*64+n] ----
        f32x4 sA[4][4];
#pragma unroll
        for (int mf = 0; mf < 4; ++mf)
#pragma unroll
            for (int nf = 0; nf < 4; ++nf) sA[mf][nf] = (f32x4){0.f, 0.f, 0.f, 0.f};
#pragma unroll
        for (int ks = 0; ks < 2; ++ks) {
            u32x4 bf[4];
#pragma unroll
            for (int nf = 0; nf < 4; ++nf) {
                const int srow = c * 64 + nf * 16 + cl;
                bf[nf] = *(const u32x4*)(Klds + srow * 64 +
                                         (((ks * 4 + kg) ^ (srow & 7)) << 3));
            }
#pragma unroll
            for (int mf = 0; mf < 4; ++mf)
#pragma unroll
                for (int nf = 0; nf < 4; ++nf)
                    sA[mf][nf] = mfma16(qreg[mf][ks], bf[nf], sA[mf][nf]);
        }
        // ---- mask bias + online softmax + P write ----
#pragma unroll
        for (int mf = 0; mf < 4; ++mf)
#pragma unroll
            for (int nf = 0; nf < 4; ++nf) {
                const float mb = mbias[c * 4 + nf];
                sA[mf][nf] += (f32x4){mb, mb, mb, mb};
            }
#pragma unroll
        for (int mf = 0; mf < 4; ++mf) {
            f32x4 fv;
#pragma unroll
            for (int r = 0; r < 4; ++r) {
                float rm = fmaxf(fmaxf(sA[mf][0][r], sA[mf][1][r]),
                                 fmaxf(sA[mf][2][r], sA[mf][3][r]));
                rm = fmaxf(rm, __shfl_xor(rm, 1));
                rm = fmaxf(rm, __shfl_xor(rm, 2));
                rm = fmaxf(rm, __shfl_xor(rm, 4));
                rm = fmaxf(rm, __shfl_xor(rm, 8));
                const float mo = mrow[mf][r];
                const float mn = fmaxf(mo, rm);
                const float f = exp2i(C2 * (mo - mn));
                mrow[mf][r] = mn;
                float p0 = exp2i(C2 * (sA[mf][0][r] - mn));
                float p1 = exp2i(C2 * (sA[mf][1][r] - mn));
                float p2 = exp2i(C2 * (sA[mf][2][r] - mn));
                float p3 = exp2i(C2 * (sA[mf][3][r] - mn));
                float ps = p0 + p1 + p2 + p3;
                ps += __shfl_xor(ps, 1);
                ps += __shfl_xor(ps, 2);
                ps += __shfl_xor(ps, 4);
                ps += __shfl_xor(ps, 8);
                lrowv[mf][r] = lrowv[mf][r] * f + ps;
                fv[r] = f;
                // write P pair-packed (cols cl,cl+1 from lanes cl even)
                const int m = mf * 16 + rg * 4 + r;
                const int mbase = (wave << 12) + m * 64;
                float q0 = __shfl_xor(p0, 1);
                float q1 = __shfl_xor(p1, 1);
                float q2 = __shfl_xor(p2, 1);
                float q3 = __shfl_xor(p3, 1);
                if ((cl & 1) == 0) {
                    const int e0 = mbase + (((0 + (cl >> 3)) ^ (m & 7)) << 3) + (cl & 7);
                    const int e1 = mbase + (((2 + (cl >> 3)) ^ (m & 7)) << 3) + (cl & 7);
                    const int e2 = mbase + (((4 + (cl >> 3)) ^ (m & 7)) << 3) + (cl & 7);
                    const int e3 = mbase + (((6 + (cl >> 3)) ^ (m & 7)) << 3) + (cl & 7);
                    *(unsigned*)(Plds + e0) = (unsigned)f2bf(p0) | ((unsigned)f2bf(q0) << 16);
                    *(unsigned*)(Plds + e1) = (unsigned)f2bf(p1) | ((unsigned)f2bf(q1) << 16);
                    *(unsigned*)(Plds + e2) = (unsigned)f2bf(p2) | ((unsigned)f2bf(q2) << 16);
                    *(unsigned*)(Plds + e3) = (unsigned)f2bf(p3) | ((unsigned)f2bf(q3) << 16);
                }
            }
#pragma unroll
            for (int no = 0; no < 4; ++no) accO[mf][no] *= fv;
        }
        // ---- PV chunk: O += P[64x64] * V[chunk][64] ----
#pragma unroll
        for (int ks = 0; ks < 2; ++ks) {
            u32x4 af[4], bv[4];
#pragma unroll
            for (int mf = 0; mf < 4; ++mf) {
                const int arow = mf * 16 + cl;
                af[mf] = *(const u32x4*)(Plds + (wave << 12) + arow * 64 +
                                         (((ks * 4 + kg) ^ (arow & 7)) << 3));
            }
#pragma unroll
            for (int no = 0; no < 4; ++no) {
                const int vrow = no * 16 + cl;
                const int cc = c * 8 + ks * 4 + kg;
                bv[no] = *(const u32x4*)(Vlds + vrow * 256 + ((cc ^ (vrow & 7)) << 3));
            }
#pragma unroll
            for (int mf = 0; mf < 4; ++mf)
#pragma unroll
                for (int no = 0; no < 4; ++no)
                    accO[mf][no] = mfma16(af[mf], bv[no], accO[mf][no]);
        }
    }

    // ---- normalize + write O into qbuf (own head cols only) ----
#pragma unroll
    for (int mf = 0; mf < 4; ++mf) {
        float inv[4];
#pragma unroll
        for (int r = 0; r < 4; ++r) inv[r] = 1.0f / lrowv[mf][r];
#pragma unroll
        for (int no = 0; no < 4; ++no)
#pragma unroll
            for (int r = 0; r < 4; ++r) {
                const float ov = accO[mf][no][r] * inv[r];
                const float oo = __shfl_xor(ov, 1);
                if ((cl & 1) == 0) {
                    const int m = mf * 16 + rg * 4 + r;
                    const size_t tok = (size_t)(bb * 256 + wave * 64 + m);
                    *(unsigned*)(outp + tok * H + hh * 64 + no * 16 + cl) =
                        (unsigned)f2bf(ov) | ((unsigned)f2bf(oo) << 16);
                }
            }
    }
}

// ---------------- all 6 weight transposes of one layer, one dispatch ----------------
__global__ __launch_bounds__(256) void transpose_all_k(
    const float* __restrict__ Wq, const float* __restrict__ Wk,
    const float* __restrict__ Wv, const float* __restrict__ Wo,
    const float* __restrict__ W1, const float* __restrict__ W2,
    ushortT* __restrict__ wtqkv, ushortT* __restrict__ wto,
    ushortT* __restrict__ wt1, ushortT* __restrict__ wt2)
{
    int idx = blockIdx.x;
    const float* W; ushortT* WT; int R, C, tr, tc;
    if (idx < 2304) {
        int mat = idx / 576, t = idx - mat * 576;
        tr = t / 24; tc = t - tr * 24; R = 768; C = 768;
        W = mat == 0 ? Wq : mat == 1 ? Wk : mat == 2 ? Wv : Wo;
        WT = mat < 3 ? wtqkv + (size_t)mat * 768 * 768 : wto;
    } else if (idx < 4608) {
        int t = idx - 2304; tr = t / 96; tc = t - tr * 96;
        R = 768; C = 3072; W = W1; WT = wt1;
    } else {
        int t = idx - 4608; tr = t / 24; tc = t - tr * 24;
        R = 3072; C = 768; W = W2; WT = wt2;
    }
    int r0 = tr * 32, c0 = tc * 32;
    __shared__ float tl[32][33];
    int trd = threadIdx.x >> 3;
    int tc4 = (threadIdx.x & 7) * 4;
    const float4 v = *(const float4*)(W + (size_t)(r0 + trd) * C + c0 + tc4);
    tl[trd][tc4 + 0] = v.x; tl[trd][tc4 + 1] = v.y;
    tl[trd][tc4 + 2] = v.z; tl[trd][tc4 + 3] = v.w;
    __syncthreads();
    u16x4 o;
#pragma unroll
    for (int q = 0; q < 4; ++q) o[q] = f2bf(tl[tc4 + q][trd]);
    *(u16x4*)(WT + (size_t)(c0 + trd) * R + r0 + tc4) = o;
}

// ---------------- pack qkv biases -> [NLAY][2304] ----------------
__global__ __launch_bounds__(256) void pack_bias_k(
    const float* __restrict__ bq, const float* __restrict__ bk,
    const float* __restrict__ bv, float* __restrict__ out)
{
    int l = blockIdx.x / 3, r = blockIdx.x - (blockIdx.x / 3) * 3;
    const float* src = r == 0 ? bq : r == 1 ? bk : bv;
#pragma unroll
    for (int j = 0; j < 3; ++j) {
        int d = threadIdx.x + 256 * j;
        out[(size_t)l * QKVN + r * H + d] = src[(size_t)l * H + d];
    }
}

// ---------------- block reduce helper ----------------
__device__ inline void blk_reduce2(float& s, float& ss, float* red) {
#pragma unroll
    for (int m = 32; m; m >>= 1) { s += __shfl_xor(s, m); ss += __shfl_xor(ss, m); }
    int w = threadIdx.x >> 6;
    if ((threadIdx.x & 63) == 0) { red[w] = s; red[4 + w] = ss; }
    __syncthreads();
    s = red[0] + red[1] + red[2] + red[3];
    ss = red[4] + red[5] + red[6] + red[7];
}

// ---------------- embeddings + LN (emit f32 + bf16) ----------------
__global__ __launch_bounds__(256) void embed_ln_k(
    const int* __restrict__ ids, const int* __restrict__ tts,
    const float* __restrict__ wemb, const float* __restrict__ pemb,
    const float* __restrict__ temb, const float* __restrict__ g,
    const float* __restrict__ bp, float* __restrict__ h, ushortT* __restrict__ hb)
{
    int tok = blockIdx.x, tid = threadIdx.x;
    int spos = tok & (S - 1);
    int id = ids[tok], tt = tts[tok];
    const float* wr = wemb + (size_t)id * H;
    const float* pr = pemb + (size_t)spos * H;
    const float* tr = temb + (size_t)tt * H;
    float x[3]; float s = 0.f, ss = 0.f;
#pragma unroll
    for (int j = 0; j < 3; ++j) {
        int d = tid + 256 * j;
        x[j] = wr[d] + pr[d] + tr[d];
        s += x[j]; ss += x[j] * x[j];
    }
    __shared__ float red[8];
    blk_reduce2(s, ss, red);
    float mu = s * (1.f / H);
    float var = ss * (1.f / H) - mu * mu;
    float rs = rsqrtf(var + 1e-12f);
#pragma unroll
    for (int j = 0; j < 3; ++j) {
        int d = tid + 256 * j;
        float y = (x[j] - mu) * rs * g[d] + bp[d];
        h[(size_t)tok * H + d] = y;
        hb[(size_t)tok * H + d] = f2bf(y);
    }
}

// ---------------- residual add (bf16 operand) + LN, in place on h ----------------
__global__ __launch_bounds__(256) void add_ln_k(
    float* __restrict__ h, const ushortT* __restrict__ add,
    const float* __restrict__ g, const float* __restrict__ bp,
    ushortT* __restrict__ hb)
{
    int tok = blockIdx.x, tid = threadIdx.x;
    float x[3]; float s = 0.f, ss = 0.f;
#pragma unroll
    for (int j = 0; j < 3; ++j) {
        int d = tid + 256 * j;
        x[j] = h[(size_t)tok * H + d] + bf2f(add[(size_t)tok * H + d]);
        s += x[j]; ss += x[j] * x[j];
    }
    __shared__ float red[8];
    blk_reduce2(s, ss, red);
    float mu = s * (1.f / H);
    float var = ss * (1.f / H) - mu * mu;
    float rs = rsqrtf(var + 1e-12f);
#pragma unroll
    for (int j = 0; j < 3; ++j) {
        int d = tid + 256 * j;
        float y = (x[j] - mu) * rs * g[d] + bp[d];
        h[(size_t)tok * H + d] = y;
        hb[(size_t)tok * H + d] = f2bf(y);
    }
}

// ---------------- logits + log_softmax over 9 labels (f32 exact) ----------------
__global__ __launch_bounds__(256) void logits_k(
    const float* __restrict__ h, const float* __restrict__ fcw, float* __restrict__ em)
{
    int tok = blockIdx.x, tid = threadIdx.x;
    float p[LBL];
#pragma unroll
    for (int l = 0; l < LBL; ++l) p[l] = 0.f;
    const float* hr = h + (size_t)tok * H;
#pragma unroll
    for (int j = 0; j < 3; ++j) {
        int d = tid + 256 * j;
        float hv = hr[d];
        const float* fr = fcw + (size_t)d * LBL;
#pragma unroll
        for (int l = 0; l < LBL; ++l) p[l] = fmaf(hv, fr[l], p[l]);
    }
    __shared__ float ls[4][LBL];
    __shared__ float lg[LBL];
    __shared__ float lse;
#pragma unroll
    for (int l = 0; l < LBL; ++l) {
        float v = p[l];
#pragma unroll
        for (int m = 32; m; m >>= 1) v += __shfl_xor(v, m);
        if ((tid & 63) == 0) ls[tid >> 6][l] = v;
    }
    __syncthreads();
    if (tid < LBL) lg[tid] = ls[0][tid] + ls[1][tid] + ls[2][tid] + ls[3][tid];
    __syncthreads();
    if (tid == 0) {
        float mx = lg[0];
#pragma unroll
        for (int j = 1; j < LBL; ++j) mx = fmaxf(mx, lg[j]);
        float sm = 0.f;
#pragma unroll
        for (int j = 0; j < LBL; ++j) sm += expf(lg[j] - mx);
        lse = mx + logf(sm);
    }
    __syncthreads();
    if (tid < LBL) em[(size_t)tok * LBL + tid] = lg[tid] - lse;
}

// ---------------- CRF: one wave per batch elem, base-2 fast recursion ----------------
__global__ __launch_bounds__(64) void crf_k(
    const float* __restrict__ em, const int* __restrict__ tags,
    const int* __restrict__ mask, const float* __restrict__ sp,
    const float* __restrict__ ep, const float* __restrict__ trans,
    float* __restrict__ partial)
{
    constexpr float LOG2E = 1.4426950408889634f;
    constexpr float LN2   = 0.6931471805599453f;
    int b = blockIdx.x, t = threadIdx.x;
    __shared__ float eml[S * LBL];     // emissions * log2(e)
    __shared__ int mkl[S];
    const float* emb = em + (size_t)b * S * LBL;
    const int* tg = tags + (size_t)b * S;
    const int* mk = mask + (size_t)b * S;

    for (int i = t * 4; i < S * LBL; i += 256) {
        float4 v = *(const float4*)&emb[i];
        v.x *= LOG2E; v.y *= LOG2E; v.z *= LOG2E; v.w *= LOG2E;
        *(float4*)&eml[i] = v;
    }
    *(i32x4*)&mkl[t * 4] = *(const i32x4*)&mk[t * 4];

    int cnt = 0; float ns = 0.f;
    for (int i = t; i < S; i += 64) {
        int m = mk[i];
        cnt += (m != 0);
        if (i >= 1 && m)
            ns += trans[tg[i - 1] * LBL + tg[i]] + emb[(size_t)i * LBL + tg[i]];
    }
#pragma unroll
    for (int m = 32; m; m >>= 1) { cnt += __shfl_xor(cnt, m); ns += __shfl_xor(ns, m); }
    float num = ns + sp[tg[0]] + emb[tg[0]] + ep[tg[cnt - 1]];

    int tt = t < LBL ? t : 0;
    float trc2[LBL];
#pragma unroll
    for (int i = 0; i < LBL; ++i) trc2[i] = trans[i * LBL + tt] * LOG2E;

    __syncthreads();

    float alpha2 = (t < LBL) ? sp[t] * LOG2E + eml[t] : -1e30f;
    for (int step = 1; step < S; ++step) {
        float av[LBL];
#pragma unroll
        for (int i = 0; i < LBL; ++i) av[i] = __shfl(alpha2, i) + trc2[i];
        float mx = av[0];
#pragma unroll
        for (int i = 1; i < LBL; ++i) mx = fmaxf(mx, av[i]);
        float sm = 0.f;
#pragma unroll
        for (int i = 0; i < LBL; ++i) sm += exp2i(av[i] - mx);
        float na = mx + log2i(sm) + eml[step * LBL + tt];
        alpha2 = (mkl[step] && t < LBL) ? na : alpha2;
    }
    float z = (t < LBL) ? alpha2 + ep[t] * LOG2E : -1e30f;
    float mx = z;
#pragma unroll
    for (int m = 8; m; m >>= 1) mx = fmaxf(mx, __shfl_xor(mx, m));
    float sm = exp2i(z - mx);
#pragma unroll
    for (int m = 8; m; m >>= 1) sm += __shfl_xor(sm, m);
    if (t == 0) partial[b] = (mx + log2i(sm)) * LN2 - num;
}

__global__ void finalize_k(const float* __restrict__ partial, float* __restrict__ out) {
    float s = 0.f;
    for (int i = 0; i < BATCH; ++i) s += partial[i];
    out[0] = s;
}

__global__ void sentinel_k(float* out) { out[0] = -12345.0f; }

extern "C" void kernel_launch(void* const* d_in, const int* in_sizes, int n_in,
                              void* d_out, int out_size, void* d_ws, size_t ws_size,
                              hipStream_t stream) {
    (void)in_sizes; (void)n_in; (void)out_size;
    const int* token_ids  = (const int*)d_in[0];
    const int* token_type = (const int*)d_in[1];
    const int* amask      = (const int*)d_in[2];
    const int* y          = (const int*)d_in[3];
    const float* wemb = (const float*)d_in[4];
    const float* pemb = (const float*)d_in[5];
    const float* temb = (const float*)d_in[6];
    const float* eg   = (const float*)d_in[7];
    const float* eb   = (const float*)d_in[8];
    const float* Wq = (const float*)d_in[9];
    const float* bq = (const float*)d_in[10];
    const float* Wk = (const float*)d_in[11];
    const float* bk = (const float*)d_in[12];
    const float* Wv = (const float*)d_in[13];
    const float* bv = (const float*)d_in[14];
    const float* Wo = (const float*)d_in[15];
    const float* bo = (const float*)d_in[16];
    const float* ln1g = (const float*)d_in[17];
    const float* ln1b = (const float*)d_in[18];
    const float* W1 = (const float*)d_in[19];
    const float* b1 = (const float*)d_in[20];
    const float* W2 = (const float*)d_in[21];
    const float* b2 = (const float*)d_in[22];
    const float* ln2g = (const float*)d_in[23];
    const float* ln2b = (const float*)d_in[24];
    const float* fcw = (const float*)d_in[25];
    const float* crf_s = (const float*)d_in[26];
    const float* crf_e = (const float*)d_in[27];
    const float* crf_t = (const float*)d_in[28];

    if (ws_size < WS_FLOATS * sizeof(float)) {
        sentinel_k<<<1, 1, 0, stream>>>((float*)d_out);
        return;
    }

    float* ws = (float*)d_ws;
    float*   hbuf = ws + H_OFF;
    ushortT* hb   = (ushortT*)(ws + HB_OFF);
    ushortT* qb   = (ushortT*)(ws + QB_OFF);   // q base; k = +TOKENS*H; vt = +2*TOKENS*H
    ushortT* kb   = (ushortT*)(ws + KB_OFF);
    ushortT* vt   = (ushortT*)(ws + VT_OFF);
    ushortT* big  = (ushortT*)(ws + BIG_OFF);
    ushortT* wtq  = (ushortT*)(ws + WTQ_OFF);  // [2304][768]
    ushortT* wto  = (ushortT*)(ws + WTO_OFF);
    ushortT* wt1  = (ushortT*)(ws + WT1_OFF);
    ushortT* wt2  = (ushortT*)(ws + WT2_OFF);
    float*   embuf = ws + EM_OFF;
    float*   part  = ws + PART_OFF;
    float*   bqkv  = ws + BQKV_OFF;

    pack_bias_k<<<NLAY * 3, 256, 0, stream>>>(bq, bk, bv, bqkv);
    embed_ln_k<<<TOKENS, 256, 0, stream>>>(token_ids, token_type, wemb, pemb, temb,
                                           eg, eb, hbuf, hb);

    constexpr long long HH = (long long)H * H;
    constexpr long long HF = (long long)H * FF;

    dim3 gQKV(QKVN / 128, TOKENS / 128, 1);    // 18 x 64
    dim3 gProj(H / 128, TOKENS / 128, 1);      // 6 x 64
    dim3 gFF1(FF / 128, TOKENS / 128, 1);      // 24 x 64

    for (int l = 0; l < NLAY; ++l) {
        transpose_all_k<<<6912, 256, 0, stream>>>(
            Wq + l * HH, Wk + l * HH, Wv + l * HH, Wo + l * HH,
            W1 + l * HF, W2 + l * HF, wtq, wto, wt1, wt2);

        // fused q,k,v projections (2-phase 128^2 with routing epilogue)
        gemm_mfma<2,2,5><<<gQKV, 256, 0, stream>>>(
            hb, H, 0, 0, wtq, H, 0, 0, bqkv + (size_t)l * QKVN,
            qb, H, 0, 0, H, 1);

        // fused attention: QK^T + softmax + PV, ctx overwrites q in qb
        attn_fused_k<<<BATCH * NHD, 256, 0, stream>>>(qb, kb, vt, amask, qb);

        // attention output projection -> kb (bf16)
        gemm_mfma<2,2,0><<<gProj, 256, 0, stream>>>(
            qb, H, 0, 0, wto, H, 0, 0, bo + l * H, kb, H, 0, 0, H, 1);

        add_ln_k<<<TOKENS, 256, 0, stream>>>(hbuf, kb, ln1g + l * H, ln1b + l * H, hb);

        // ff1 = gelu(h @ W1 + b1) -> big bf16
        gemm_mfma<2,2,1><<<gFF1, 256, 0, stream>>>(
            hb, H, 0, 0, wt1, H, 0, 0, b1 + (long long)l * FF, big, FF, 0, 0, H, 1);

        // ff2 -> qb (bf16)
        gemm_mfma<2,2,0><<<gProj, 256, 0, stream>>>(
            big, FF, 0, 0, wt2, FF, 0, 0, b2 + l * H, qb, H, 0, 0, FF, 1);

        add_ln_k<<<TOKENS, 256, 0, stream>>>(hbuf, qb, ln2g + l * H, ln2b + l * H, hb);
    }

    logits_k<<<TOKENS, 256, 0, stream>>>(hbuf, fcw, embuf);
    crf_k<<<BATCH, 64, 0, stream>>>(embuf, y, amask, crf_s, crf_e, crf_t, part);
    finalize_k<<<1, 1, 0, stream>>>(part, (float*)d_out);
}

// Round 8
// 3537.985 us; speedup vs baseline: 1.1100x; 1.1100x over previous
//
#include <hip/hip_runtime.h>
#include <math.h>

typedef unsigned short ushortT;
typedef __attribute__((ext_vector_type(4))) float f32x4;
typedef __attribute__((ext_vector_type(4))) unsigned int u32x4;
typedef __attribute__((ext_vector_type(4))) unsigned short u16x4;
typedef __attribute__((ext_vector_type(4))) int i32x4;
typedef __attribute__((ext_vector_type(8))) __bf16 bf16x8;

namespace {
constexpr int S = 256;
constexpr int H = 768;
constexpr int NLAY = 12;
constexpr int NHD = 12;
constexpr int FF = 3072;
constexpr int LBL = 9;
constexpr int DH = 64;
constexpr int BATCH = 32;
constexpr int TOKENS = BATCH * S;      // 8192
constexpr int QKVN = 3 * H;            // 2304
constexpr float SCALE = 0.125f;        // 1/sqrt(64)

// workspace layout (float-slot units)
constexpr size_t H_OFF   = 0;                          // h f32 [8192*768]
constexpr size_t HB_OFF  = H_OFF + (size_t)TOKENS*H;   // h bf16 (half slots)
constexpr size_t QB_OFF  = HB_OFF + (size_t)TOKENS*H/2;  // q / ctx / ff2out bf16
constexpr size_t KB_OFF  = QB_OFF + (size_t)TOKENS*H/2;  // k / attn-out bf16
constexpr size_t VT_OFF  = KB_OFF + (size_t)TOKENS*H/2;  // v^T bf16 [B*NH*DH][S]
constexpr size_t BIG_OFF = VT_OFF + (size_t)TOKENS*H/2;  // scores bf16 == ff1 bf16
constexpr size_t WTQ_OFF = BIG_OFF + (size_t)TOKENS*FF/2;  // Wq^T,Wk^T,Wv^T contiguous
constexpr size_t WTO_OFF = WTQ_OFF + 3*(size_t)H*H/2;
constexpr size_t WT1_OFF = WTO_OFF + (size_t)H*H/2;      // W1^T [3072][768]
constexpr size_t WT2_OFF = WT1_OFF + (size_t)H*FF/2;     // W2^T [768][3072]
constexpr size_t EM_OFF  = WT2_OFF + (size_t)H*FF/2;
constexpr size_t PART_OFF= EM_OFF + (size_t)TOKENS*LBL;
constexpr size_t BQKV_OFF= PART_OFF + 64;                // packed qkv bias [12][2304]
constexpr size_t WS_FLOATS = BQKV_OFF + (size_t)NLAY*QKVN;
}

__device__ __forceinline__ ushortT f2bf(float x) {
    unsigned u = __builtin_bit_cast(unsigned, x);
    u += 0x7fffu + ((u >> 16) & 1u);
    return (ushortT)(u >> 16);
}
__device__ __forceinline__ float bf2f(ushortT h) {
    unsigned u = ((unsigned)h) << 16;
    return __builtin_bit_cast(float, u);
}

__device__ __forceinline__ float exp2i(float x) {
    float r; asm("v_exp_f32 %0, %1" : "=v"(r) : "v"(x)); return r;
}
__device__ __forceinline__ float log2i(float x) {
    float r; asm("v_log_f32 %0, %1" : "=v"(r) : "v"(x)); return r;
}

// tanh-gelu in sigmoid form: 0.5x(1+tanh(u)) == x*sigmoid(2u) == x/(1+exp2(-2u*log2e))
__device__ __forceinline__ float gelu_tanh(float x) {
    float u = 0.7978845608028654f * (x + 0.044715f * x * x * x);
    float t = exp2i(-2.8853900817779268f * u);
    return x / (1.0f + t);
}

__device__ __forceinline__ f32x4 mfma16(u32x4 a, u32x4 b, f32x4 c) {
    return __builtin_amdgcn_mfma_f32_16x16x32_bf16(
        __builtin_bit_cast(bf16x8, a), __builtin_bit_cast(bf16x8, b), c, 0, 0, 0);
}

__device__ __forceinline__ void gload_lds16(const ushortT* g, ushortT* l) {
    __builtin_amdgcn_global_load_lds(
        (const __attribute__((address_space(1))) unsigned int*)g,
        (__attribute__((address_space(3))) unsigned int*)l,
        16, 0, 0);
}

// ---------------- bf16 MFMA GEMM, double-buffered 2-phase (128^2 / 256x64) ----------------
// C[m,n] = epi( sum_k A[m,k]*Bt[n,k] + bias[n] )
// MODE: 0 = bf16 + bias | 1 = bf16 + bias + gelu | 4 = bf16, no bias
//       | 5 = fused-QKV routing (Cv = q base; k at +TOKENS*H; v^T per head at +2*TOKENS*H)
// 2D grids (gridDim.z==1) get the XCD-aware bijective block swizzle (T1).
template<int WM, int WN, int MODE>
__global__ __launch_bounds__(256) void gemm_mfma(
    const ushortT* __restrict__ A, int lda, long long sAo, long long sAi,
    const ushortT* __restrict__ Bt, int ldb, long long sBo, long long sBi,
    const float* __restrict__ bias,
    void* __restrict__ Cv, int ldc, long long sCo, long long sCi,
    int K, int innerN)
{
    constexpr int BM = WM * 64, BN = WN * 64;
    __shared__ __align__(16) ushortT As[2][BM * 32];
    __shared__ __align__(16) ushortT Bs[2][BN * 32];
    const int tid = threadIdx.x;
    const int wave = tid >> 6, lane = tid & 63;
    const int ob = blockIdx.z / innerN, ib = blockIdx.z - ob * innerN;

    int bxi = blockIdx.x, byi = blockIdx.y;
    if (gridDim.z == 1) {
        // XCD swizzle: contiguous chunks per XCD (grids are %8==0)
        const int nwg = gridDim.x * gridDim.y;
        const int lin = byi * gridDim.x + bxi;
        const int cpx = nwg >> 3;
        const int sw = (lin & 7) * cpx + (lin >> 3);
        byi = sw / gridDim.x; bxi = sw - byi * gridDim.x;
    }
    const int bm = byi * BM, bn = bxi * BN;
    const ushortT* Ab = A + ob * sAo + ib * sAi + (size_t)bm * lda;
    const ushortT* Bb = Bt + ob * sBo + ib * sBi + (size_t)bn * ldb;
    const int wm = wave / WN, wn = wave - wm * WN;

    const int lrow = lane >> 2;
    const int lk16 = (lane & 3) * 8;
    const int rl = lane & 15;
    const int kg = (lane >> 4) * 8;

    f32x4 acc[4][4];
#pragma unroll
    for (int i = 0; i < 4; ++i)
#pragma unroll
        for (int j = 0; j < 4; ++j) acc[i][j] = (f32x4){0.f, 0.f, 0.f, 0.f};

    auto stage = [&](int buf, int k0) {
#pragma unroll
        for (int j = 0; j < WM; ++j) {
            int chunk = j * 4 + wave;
            gload_lds16(Ab + (size_t)(chunk * 16 + lrow) * lda + k0 + lk16,
                        &As[buf][chunk * 512]);
        }
#pragma unroll
        for (int j = 0; j < WN; ++j) {
            int chunk = j * 4 + wave;
            gload_lds16(Bb + (size_t)(chunk * 16 + lrow) * ldb + k0 + lk16,
                        &Bs[buf][chunk * 512]);
        }
    };

    stage(0, 0);
    __syncthreads();
    const int nt = K >> 5;
    int cur = 0;
    for (int t = 0; t < nt; ++t) {
        if (t + 1 < nt) stage(cur ^ 1, (t + 1) << 5);
        u32x4 a[4], b[4];
#pragma unroll
        for (int mf = 0; mf < 4; ++mf)
            a[mf] = *(const u32x4*)&As[cur][(wm * 64 + mf * 16 + rl) * 32 + kg];
#pragma unroll
        for (int nf = 0; nf < 4; ++nf)
            b[nf] = *(const u32x4*)&Bs[cur][(wn * 64 + nf * 16 + rl) * 32 + kg];
#pragma unroll
        for (int mf = 0; mf < 4; ++mf)
#pragma unroll
            for (int nf = 0; nf < 4; ++nf)
                acc[mf][nf] = mfma16(a[mf], b[nf], acc[mf][nf]);
        __syncthreads();
        cur ^= 1;
    }

    ushortT* Ch = (ushortT*)Cv + ob * sCo + ib * sCi;
#pragma unroll
    for (int nf = 0; nf < 4; ++nf) {
        int gn = bn + wn * 64 + nf * 16 + rl;
        float bv = 0.f;
        if constexpr (MODE != 4) bv = bias[gn];
#pragma unroll
        for (int mf = 0; mf < 4; ++mf) {
            int gm = bm + wm * 64 + mf * 16 + ((lane >> 4) << 2);
            if constexpr (MODE == 5) {
                const int region = gn / H;          // 0=q,1=k,2=v
                const int col = gn - region * H;
                if (region < 2) {
                    ushortT* o = (ushortT*)Cv + (size_t)region * TOKENS * H;
#pragma unroll
                    for (int r = 0; r < 4; ++r)
                        o[(size_t)(gm + r) * H + col] = f2bf(acc[mf][nf][r] + bv);
                } else {
                    u16x4 o;
#pragma unroll
                    for (int r = 0; r < 4; ++r) o[r] = f2bf(acc[mf][nf][r] + bv);
                    const int b_ = gm >> 8, s0 = gm & 255;
                    const int h_ = col >> 6, dh = col & 63;
                    *(u16x4*)((ushortT*)Cv + 2 * (size_t)TOKENS * H +
                              (((size_t)(b_ * NHD + h_) * DH + dh) << 8) + s0) = o;
                }
            } else {
#pragma unroll
                for (int r = 0; r < 4; ++r) {
                    float x = acc[mf][nf][r] + bv;
                    if constexpr (MODE == 1) x = gelu_tanh(x);
                    Ch[(size_t)(gm + r) * ldc + gn] = f2bf(x);
                }
            }
        }
    }
}

// ---------------- scale + mask + softmax on bf16 scores (in place) ----------------
// grid: B*NH*(S/16); 16 rows/block, 16 lanes per row, 16 elems per lane, no LDS
__global__ __launch_bounds__(256) void attn_softmax_bf16_k(
    ushortT* __restrict__ att, const int* __restrict__ mask)
{
    int blk = blockIdx.x, tid = threadIdx.x;
    int bh = blk >> 4;
    int r0 = (blk & 15) * 16;
    int b = bh / NHD;
    int r = tid >> 4, c0 = (tid & 15) * 16;
    ushortT* rp = att + ((size_t)bh * S + r0 + r) * S;
    const int* mrow = mask + (size_t)b * S;

    u32x4 x0 = *(const u32x4*)(rp + c0);
    u32x4 x1 = *(const u32x4*)(rp + c0 + 8);
    unsigned w[8];
    *(u32x4*)&w[0] = x0; *(u32x4*)&w[4] = x1;
    float v[16];
#pragma unroll
    for (int i = 0; i < 8; ++i) {
        v[2 * i]     = bf2f((ushortT)(w[i] & 0xffffu));
        v[2 * i + 1] = bf2f((ushortT)(w[i] >> 16));
    }
#pragma unroll
    for (int j = 0; j < 16; ++j)
        v[j] = v[j] * SCALE + (mrow[c0 + j] ? 0.f : -1e9f);
    float mx = -1e30f;
#pragma unroll
    for (int j = 0; j < 16; ++j) mx = fmaxf(mx, v[j]);
#pragma unroll
    for (int m = 8; m; m >>= 1) mx = fmaxf(mx, __shfl_xor(mx, m));
    float sum = 0.f;
#pragma unroll
    for (int j = 0; j < 16; ++j) { v[j] = expf(v[j] - mx); sum += v[j]; }
#pragma unroll
    for (int m = 8; m; m >>= 1) sum += __shfl_xor(sum, m);
    float inv = 1.f / sum;
#pragma unroll
    for (int i = 0; i < 8; ++i)
        w[i] = (unsigned)f2bf(v[2 * i] * inv) |
               ((unsigned)f2bf(v[2 * i + 1] * inv) << 16);
    *(u32x4*)(rp + c0) = *(u32x4*)&w[0];
    *(u32x4*)(rp + c0 + 8) = *(u32x4*)&w[4];
}

// ---------------- all 6 weight transposes of one layer, one dispatch ----------------
__global__ __launch_bounds__(256) void transpose_all_k(
    const float* __restrict__ Wq, const float* __restrict__ Wk,
    const float* __restrict__ Wv, const float* __restrict__ Wo,
    const float* __restrict__ W1, const float* __restrict__ W2,
    ushortT* __restrict__ wtqkv, ushortT* __restrict__ wto,
    ushortT* __restrict__ wt1, ushortT* __restrict__ wt2)
{
    int idx = blockIdx.x;
    const float* W; ushortT* WT; int R, C, tr, tc;
    if (idx < 2304) {
        int mat = idx / 576, t = idx - mat * 576;
        tr = t / 24; tc = t - tr * 24; R = 768; C = 768;
        W = mat == 0 ? Wq : mat == 1 ? Wk : mat == 2 ? Wv : Wo;
        WT = mat < 3 ? wtqkv + (size_t)mat * 768 * 768 : wto;
    } else if (idx < 4608) {
        int t = idx - 2304; tr = t / 96; tc = t - tr * 96;
        R = 768; C = 3072; W = W1; WT = wt1;
    } else {
        int t = idx - 4608; tr = t / 24; tc = t - tr * 24;
        R = 3072; C = 768; W = W2; WT = wt2;
    }
    int r0 = tr * 32, c0 = tc * 32;
    __shared__ float tl[32][33];
    int trd = threadIdx.x >> 3;
    int tc4 = (threadIdx.x & 7) * 4;
    const float4 v = *(const float4*)(W + (size_t)(r0 + trd) * C + c0 + tc4);
    tl[trd][tc4 + 0] = v.x; tl[trd][tc4 + 1] = v.y;
    tl[trd][tc4 + 2] = v.z; tl[trd][tc4 + 3] = v.w;
    __syncthreads();
    u16x4 o;
#pragma unroll
    for (int q = 0; q < 4; ++q) o[q] = f2bf(tl[tc4 + q][trd]);
    *(u16x4*)(WT + (size_t)(c0 + trd) * R + r0 + tc4) = o;
}

// ---------------- pack qkv biases -> [NLAY][2304] ----------------
__global__ __launch_bounds__(256) void pack_bias_k(
    const float* __restrict__ bq, const float* __restrict__ bk,
    const float* __restrict__ bv, float* __restrict__ out)
{
    int l = blockIdx.x / 3, r = blockIdx.x - (blockIdx.x / 3) * 3;
    const float* src = r == 0 ? bq : r == 1 ? bk : bv;
#pragma unroll
    for (int j = 0; j < 3; ++j) {
        int d = threadIdx.x + 256 * j;
        out[(size_t)l * QKVN + r * H + d] = src[(size_t)l * H + d];
    }
}

// ---------------- block reduce helper ----------------
__device__ inline void blk_reduce2(float& s, float& ss, float* red) {
#pragma unroll
    for (int m = 32; m; m >>= 1) { s += __shfl_xor(s, m); ss += __shfl_xor(ss, m); }
    int w = threadIdx.x >> 6;
    if ((threadIdx.x & 63) == 0) { red[w] = s; red[4 + w] = ss; }
    __syncthreads();
    s = red[0] + red[1] + red[2] + red[3];
    ss = red[4] + red[5] + red[6] + red[7];
}

// ---------------- embeddings + LN (emit f32 + bf16) ----------------
__global__ __launch_bounds__(256) void embed_ln_k(
    const int* __restrict__ ids, const int* __restrict__ tts,
    const float* __restrict__ wemb, const float* __restrict__ pemb,
    const float* __restrict__ temb, const float* __restrict__ g,
    const float* __restrict__ bp, float* __restrict__ h, ushortT* __restrict__ hb)
{
    int tok = blockIdx.x, tid = threadIdx.x;
    int spos = tok & (S - 1);
    int id = ids[tok], tt = tts[tok];
    const float* wr = wemb + (size_t)id * H;
    const float* pr = pemb + (size_t)spos * H;
    const float* tr = temb + (size_t)tt * H;
    float x[3]; float s = 0.f, ss = 0.f;
#pragma unroll
    for (int j = 0; j < 3; ++j) {
        int d = tid + 256 * j;
        x[j] = wr[d] + pr[d] + tr[d];
        s += x[j]; ss += x[j] * x[j];
    }
    __shared__ float red[8];
    blk_reduce2(s, ss, red);
    float mu = s * (1.f / H);
    float var = ss * (1.f / H) - mu * mu;
    float rs = rsqrtf(var + 1e-12f);
#pragma unroll
    for (int j = 0; j < 3; ++j) {
        int d = tid + 256 * j;
        float y = (x[j] - mu) * rs * g[d] + bp[d];
        h[(size_t)tok * H + d] = y;
        hb[(size_t)tok * H + d] = f2bf(y);
    }
}

// ---------------- residual add (bf16 operand) + LN, in place on h ----------------
__global__ __launch_bounds__(256) void add_ln_k(
    float* __restrict__ h, const ushortT* __restrict__ add,
    const float* __restrict__ g, const float* __restrict__ bp,
    ushortT* __restrict__ hb)
{
    int tok = blockIdx.x, tid = threadIdx.x;
    float x[3]; float s = 0.f, ss = 0.f;
#pragma unroll
    for (int j = 0; j < 3; ++j) {
        int d = tid + 256 * j;
        x[j] = h[(size_t)tok * H + d] + bf2f(add[(size_t)tok * H + d]);
        s += x[j]; ss += x[j] * x[j];
    }
    __shared__ float red[8];
    blk_reduce2(s, ss, red);
    float mu = s * (1.f / H);
    float var = ss * (1.f / H) - mu * mu;
    float rs = rsqrtf(var + 1e-12f);
#pragma unroll
    for (int j = 0; j < 3; ++j) {
        int d = tid + 256 * j;
        float y = (x[j] - mu) * rs * g[d] + bp[d];
        h[(size_t)tok * H + d] = y;
        hb[(size_t)tok * H + d] = f2bf(y);
    }
}

// ---------------- logits + log_softmax over 9 labels (f32 exact) ----------------
__global__ __launch_bounds__(256) void logits_k(
    const float* __restrict__ h, const float* __restrict__ fcw, float* __restrict__ em)
{
    int tok = blockIdx.x, tid = threadIdx.x;
    float p[LBL];
#pragma unroll
    for (int l = 0; l < LBL; ++l) p[l] = 0.f;
    const float* hr = h + (size_t)tok * H;
#pragma unroll
    for (int j = 0; j < 3; ++j) {
        int d = tid + 256 * j;
        float hv = hr[d];
        const float* fr = fcw + (size_t)d * LBL;
#pragma unroll
        for (int l = 0; l < LBL; ++l) p[l] = fmaf(hv, fr[l], p[l]);
    }
    __shared__ float ls[4][LBL];
    __shared__ float lg[LBL];
    __shared__ float lse;
#pragma unroll
    for (int l = 0; l < LBL; ++l) {
        float v = p[l];
#pragma unroll
        for (int m = 32; m; m >>= 1) v += __shfl_xor(v, m);
        if ((tid & 63) == 0) ls[tid >> 6][l] = v;
    }
    __syncthreads();
    if (tid < LBL) lg[tid] = ls[0][tid] + ls[1][tid] + ls[2][tid] + ls[3][tid];
    __syncthreads();
    if (tid == 0) {
        float mx = lg[0];
#pragma unroll
        for (int j = 1; j < LBL; ++j) mx = fmaxf(mx, lg[j]);
        float sm = 0.f;
#pragma unroll
        for (int j = 0; j < LBL; ++j) sm += expf(lg[j] - mx);
        lse = mx + logf(sm);
    }
    __syncthreads();
    if (tid < LBL) em[(size_t)tok * LBL + tid] = lg[tid] - lse;
}

// ---------------- CRF: one wave per batch elem, base-2 fast recursion ----------------
__global__ __launch_bounds__(64) void crf_k(
    const float* __restrict__ em, const int* __restrict__ tags,
    const int* __restrict__ mask, const float* __restrict__ sp,
    const float* __restrict__ ep, const float* __restrict__ trans,
    float* __restrict__ partial)
{
    constexpr float LOG2E = 1.4426950408889634f;
    constexpr float LN2   = 0.6931471805599453f;
    int b = blockIdx.x, t = threadIdx.x;
    __shared__ float eml[S * LBL];     // emissions * log2(e)
    __shared__ int mkl[S];
    const float* emb = em + (size_t)b * S * LBL;
    const int* tg = tags + (size_t)b * S;
    const int* mk = mask + (size_t)b * S;

    for (int i = t * 4; i < S * LBL; i += 256) {
        float4 v = *(const float4*)&emb[i];
        v.x *= LOG2E; v.y *= LOG2E; v.z *= LOG2E; v.w *= LOG2E;
        *(float4*)&eml[i] = v;
    }
    *(i32x4*)&mkl[t * 4] = *(const i32x4*)&mk[t * 4];

    int cnt = 0; float ns = 0.f;
    for (int i = t; i < S; i += 64) {
        int m = mk[i];
        cnt += (m != 0);
        if (i >= 1 && m)
            ns += trans[tg[i - 1] * LBL + tg[i]] + emb[(size_t)i * LBL + tg[i]];
    }
#pragma unroll
    for (int m = 32; m; m >>= 1) { cnt += __shfl_xor(cnt, m); ns += __shfl_xor(ns, m); }
    float num = ns + sp[tg[0]] + emb[tg[0]] + ep[tg[cnt - 1]];

    int tt = t < LBL ? t : 0;
    float trc2[LBL];
#pragma unroll
    for (int i = 0; i < LBL; ++i) trc2[i] = trans[i * LBL + tt] * LOG2E;

    __syncthreads();

    float alpha2 = (t < LBL) ? sp[t] * LOG2E + eml[t] : -1e30f;
    for (int step = 1; step < S; ++step) {
        float av[LBL];
#pragma unroll
        for (int i = 0; i < LBL; ++i) av[i] = __shfl(alpha2, i) + trc2[i];
        float mx = av[0];
#pragma unroll
        for (int i = 1; i < LBL; ++i) mx = fmaxf(mx, av[i]);
        float sm = 0.f;
#pragma unroll
        for (int i = 0; i < LBL; ++i) sm += exp2i(av[i] - mx);
        float na = mx + log2i(sm) + eml[step * LBL + tt];
        alpha2 = (mkl[step] && t < LBL) ? na : alpha2;
    }
    float z = (t < LBL) ? alpha2 + ep[t] * LOG2E : -1e30f;
    float mx = z;
#pragma unroll
    for (int m = 8; m; m >>= 1) mx = fmaxf(mx, __shfl_xor(mx, m));
    float sm = exp2i(z - mx);
#pragma unroll
    for (int m = 8; m; m >>= 1) sm += __shfl_xor(sm, m);
    if (t == 0) partial[b] = (mx + log2i(sm)) * LN2 - num;
}

__global__ void finalize_k(const float* __restrict__ partial, float* __restrict__ out) {
    float s = 0.f;
    for (int i = 0; i < BATCH; ++i) s += partial[i];
    out[0] = s;
}

__global__ void sentinel_k(float* out) { out[0] = -12345.0f; }

extern "C" void kernel_launch(void* const* d_in, const int* in_sizes, int n_in,
                              void* d_out, int out_size, void* d_ws, size_t ws_size,
                              hipStream_t stream) {
    (void)in_sizes; (void)n_in; (void)out_size;
    const int* token_ids  = (const int*)d_in[0];
    const int* token_type = (const int*)d_in[1];
    const int* amask      = (const int*)d_in[2];
    const int* y          = (const int*)d_in[3];
    const float* wemb = (const float*)d_in[4];
    const float* pemb = (const float*)d_in[5];
    const float* temb = (const float*)d_in[6];
    const float* eg   = (const float*)d_in[7];
    const float* eb   = (const float*)d_in[8];
    const float* Wq = (const float*)d_in[9];
    const float* bq = (const float*)d_in[10];
    const float* Wk = (const float*)d_in[11];
    const float* bk = (const float*)d_in[12];
    const float* Wv = (const float*)d_in[13];
    const float* bv = (const float*)d_in[14];
    const float* Wo = (const float*)d_in[15];
    const float* bo = (const float*)d_in[16];
    const float* ln1g = (const float*)d_in[17];
    const float* ln1b = (const float*)d_in[18];
    const float* W1 = (const float*)d_in[19];
    const float* b1 = (const float*)d_in[20];
    const float* W2 = (const float*)d_in[21];
    const float* b2 = (const float*)d_in[22];
    const float* ln2g = (const float*)d_in[23];
    const float* ln2b = (const float*)d_in[24];
    const float* fcw = (const float*)d_in[25];
    const float* crf_s = (const float*)d_in[26];
    const float* crf_e = (const float*)d_in[27];
    const float* crf_t = (const float*)d_in[28];

    if (ws_size < WS_FLOATS * sizeof(float)) {
        sentinel_k<<<1, 1, 0, stream>>>((float*)d_out);
        return;
    }

    float* ws = (float*)d_ws;
    float*   hbuf = ws + H_OFF;
    ushortT* hb   = (ushortT*)(ws + HB_OFF);
    ushortT* qb   = (ushortT*)(ws + QB_OFF);   // q base; k = +TOKENS*H; vt = +2*TOKENS*H
    ushortT* kb   = (ushortT*)(ws + KB_OFF);
    ushortT* vt   = (ushortT*)(ws + VT_OFF);
    ushortT* big  = (ushortT*)(ws + BIG_OFF);
    ushortT* wtq  = (ushortT*)(ws + WTQ_OFF);  // [2304][768]
    ushortT* wto  = (ushortT*)(ws + WTO_OFF);
    ushortT* wt1  = (ushortT*)(ws + WT1_OFF);
    ushortT* wt2  = (ushortT*)(ws + WT2_OFF);
    float*   embuf = ws + EM_OFF;
    float*   part  = ws + PART_OFF;
    float*   bqkv  = ws + BQKV_OFF;

    pack_bias_k<<<NLAY * 3, 256, 0, stream>>>(bq, bk, bv, bqkv);
    embed_ln_k<<<TOKENS, 256, 0, stream>>>(token_ids, token_type, wemb, pemb, temb,
                                           eg, eb, hbuf, hb);

    constexpr long long HH = (long long)H * H;
    constexpr long long HF = (long long)H * FF;
    constexpr long long TOKH = (long long)S * H;        // 196608
    constexpr long long ATT_B = (long long)NHD * S * S; // 786432
    constexpr long long ATT_H = (long long)S * S;       // 65536
    constexpr long long VT_B = (long long)NHD * DH * S; // 196608
    constexpr long long VT_H = (long long)DH * S;       // 16384

    dim3 gQKV(QKVN / 128, TOKENS / 128, 1);       // 18 x 64 = 1152 (%8==0)
    dim3 gProj(H / 128, TOKENS / 128, 1);         // 6 x 64 = 384
    dim3 gFF1(FF / 128, TOKENS / 128, 1);         // 24 x 64 = 1536
    dim3 gScores(S / 128, S / 128, BATCH * NHD);  // 2 x 2 x 384
    dim3 gPV(1, 1, BATCH * NHD);                  // 256x64 tile covers head

    for (int l = 0; l < NLAY; ++l) {
        transpose_all_k<<<6912, 256, 0, stream>>>(
            Wq + l * HH, Wk + l * HH, Wv + l * HH, Wo + l * HH,
            W1 + l * HF, W2 + l * HF, wtq, wto, wt1, wt2);

        // fused q,k,v projections (2-phase 128^2 with routing epilogue)
        gemm_mfma<2,2,5><<<gQKV, 256, 0, stream>>>(
            hb, H, 0, 0, wtq, H, 0, 0, bqkv + (size_t)l * QKVN,
            qb, H, 0, 0, H, 1);

        // scores = q @ k^T  (per b,h) -> bf16
        gemm_mfma<2,2,4><<<gScores, 256, 0, stream>>>(
            qb, H, TOKH, DH, kb, H, TOKH, DH, nullptr,
            big, S, ATT_B, ATT_H, DH, NHD);

        attn_softmax_bf16_k<<<BATCH * NHD * (S / 16), 256, 0, stream>>>(big, amask);

        // ctx = probs @ v  (per b,h) -> qb as [B,S,NH,DH] bf16
        gemm_mfma<4,1,4><<<gPV, 256, 0, stream>>>(
            big, S, ATT_B, ATT_H, vt, S, VT_B, VT_H, nullptr,
            qb, H, TOKH, DH, S, NHD);

        // attention output projection -> kb (bf16)
        gemm_mfma<2,2,0><<<gProj, 256, 0, stream>>>(
            qb, H, 0, 0, wto, H, 0, 0, bo + l * H, kb, H, 0, 0, H, 1);

        add_ln_k<<<TOKENS, 256, 0, stream>>>(hbuf, kb, ln1g + l * H, ln1b + l * H, hb);

        // ff1 = gelu(h @ W1 + b1) -> big bf16
        gemm_mfma<2,2,1><<<gFF1, 256, 0, stream>>>(
            hb, H, 0, 0, wt1, H, 0, 0, b1 + (long long)l * FF, big, FF, 0, 0, H, 1);

        // ff2 -> qb (bf16)
        gemm_mfma<2,2,0><<<gProj, 256, 0, stream>>>(
            big, FF, 0, 0, wt2, FF, 0, 0, b2 + l * H, qb, H, 0, 0, FF, 1);

        add_ln_k<<<TOKENS, 256, 0, stream>>>(hbuf, qb, ln2g + l * H, ln2b + l * H, hb);
    }

    logits_k<<<TOKENS, 256, 0, stream>>>(hbuf, fcw, embuf);
    crf_k<<<BATCH, 64, 0, stream>>>(embuf, y, amask, crf_s, crf_e, crf_t, part);
    finalize_k<<<1, 1, 0, stream>>>(part, (float*)d_out);
}

// Round 9
// 3357.542 us; speedup vs baseline: 1.1697x; 1.0537x over previous
//
#include <hip/hip_runtime.h>
#include <math.h>

typedef unsigned short ushortT;
typedef __attribute__((ext_vector_type(4))) float f32x4;
typedef __attribute__((ext_vector_type(4))) unsigned int u32x4;
typedef __attribute__((ext_vector_type(4))) unsigned short u16x4;
typedef __attribute__((ext_vector_type(4))) int i32x4;
typedef __attribute__((ext_vector_type(8))) __bf16 bf16x8;

namespace {
constexpr int S = 256;
constexpr int H = 768;
constexpr int NLAY = 12;
constexpr int NHD = 12;
constexpr int FF = 3072;
constexpr int LBL = 9;
constexpr int DH = 64;
constexpr int BATCH = 32;
constexpr int TOKENS = BATCH * S;      // 8192
constexpr int QKVN = 3 * H;            // 2304
constexpr float SCALE = 0.125f;        // 1/sqrt(64)

// workspace layout (float-slot units)
constexpr size_t HB_OFF  = 0;                            // h bf16 (half slots)
constexpr size_t QB_OFF  = HB_OFF + (size_t)TOKENS*H/2;  // q / ctx / ff2out bf16
constexpr size_t KB_OFF  = QB_OFF + (size_t)TOKENS*H/2;  // k / attn-out bf16
constexpr size_t VT_OFF  = KB_OFF + (size_t)TOKENS*H/2;  // v^T bf16 [B*NH*DH][S]
constexpr size_t BIG_OFF = VT_OFF + (size_t)TOKENS*H/2;  // scores bf16 == ff1 bf16
constexpr size_t WTQ_OFF = BIG_OFF + (size_t)TOKENS*FF/2;  // Wq^T,Wk^T,Wv^T contiguous
constexpr size_t WTO_OFF = WTQ_OFF + 3*(size_t)H*H/2;
constexpr size_t WT1_OFF = WTO_OFF + (size_t)H*H/2;      // W1^T [3072][768]
constexpr size_t WT2_OFF = WT1_OFF + (size_t)H*FF/2;     // W2^T [768][3072]
constexpr size_t EM_OFF  = WT2_OFF + (size_t)H*FF/2;
constexpr size_t PART_OFF= EM_OFF + (size_t)TOKENS*LBL;
constexpr size_t BQKV_OFF= PART_OFF + 64;                // packed qkv bias [12][2304]
constexpr size_t WS_FLOATS = BQKV_OFF + (size_t)NLAY*QKVN;
}

__device__ __forceinline__ ushortT f2bf(float x) {
    unsigned u = __builtin_bit_cast(unsigned, x);
    u += 0x7fffu + ((u >> 16) & 1u);
    return (ushortT)(u >> 16);
}
__device__ __forceinline__ float bf2f(ushortT h) {
    unsigned u = ((unsigned)h) << 16;
    return __builtin_bit_cast(float, u);
}

__device__ __forceinline__ float exp2i(float x) {
    float r; asm("v_exp_f32 %0, %1" : "=v"(r) : "v"(x)); return r;
}
__device__ __forceinline__ float log2i(float x) {
    float r; asm("v_log_f32 %0, %1" : "=v"(r) : "v"(x)); return r;
}

// tanh-gelu in sigmoid form: 0.5x(1+tanh(u)) == x*sigmoid(2u) == x/(1+exp2(-2u*log2e))
__device__ __forceinline__ float gelu_tanh(float x) {
    float u = 0.7978845608028654f * (x + 0.044715f * x * x * x);
    float t = exp2i(-2.8853900817779268f * u);
    return x / (1.0f + t);
}

__device__ __forceinline__ f32x4 mfma16(u32x4 a, u32x4 b, f32x4 c) {
    return __builtin_amdgcn_mfma_f32_16x16x32_bf16(
        __builtin_bit_cast(bf16x8, a), __builtin_bit_cast(bf16x8, b), c, 0, 0, 0);
}

__device__ __forceinline__ void gload_lds16(const ushortT* g, ushortT* l) {
    __builtin_amdgcn_global_load_lds(
        (const __attribute__((address_space(1))) unsigned int*)g,
        (__attribute__((address_space(3))) unsigned int*)l,
        16, 0, 0);
}

// ---------------- bf16 MFMA GEMM, double-buffered 2-phase (128^2 / 256x64) ----------------
// C[m,n] = epi( sum_k A[m,k]*Bt[n,k] + bias[n] )
// LDS rows are 64B (32 bf16). Bank-conflict fix (T2, both-sides): the 16B slot
// within each row is XOR-swizzled with (row>>1)&3 — applied on the GLOBAL source
// chunk during staging (linear LDS dest, rule #21) and on the ds_read address.
// 16 lanes of a quarter-wave then hit 8 bank-quads x2 = 2-way = free (m136).
// MODE: 0 = bf16 + bias | 1 = bf16 + bias + gelu | 4 = bf16, no bias
//       | 5 = fused-QKV routing (Cv = q base; k at +TOKENS*H; v^T per head at +2*TOKENS*H)
// 2D grids (gridDim.z==1) get the XCD-aware block swizzle (T1); grids are %8==0.
template<int WM, int WN, int MODE>
__global__ __launch_bounds__(256) void gemm_mfma(
    const ushortT* __restrict__ A, int lda, long long sAo, long long sAi,
    const ushortT* __restrict__ Bt, int ldb, long long sBo, long long sBi,
    const float* __restrict__ bias,
    void* __restrict__ Cv, int ldc, long long sCo, long long sCi,
    int K, int innerN)
{
    constexpr int BM = WM * 64, BN = WN * 64;
    __shared__ __align__(16) ushortT As[2][BM * 32];
    __shared__ __align__(16) ushortT Bs[2][BN * 32];
    const int tid = threadIdx.x;
    const int wave = tid >> 6, lane = tid & 63;
    const int ob = blockIdx.z / innerN, ib = blockIdx.z - ob * innerN;

    int bxi = blockIdx.x, byi = blockIdx.y;
    if (gridDim.z == 1) {
        const int nwg = gridDim.x * gridDim.y;
        const int lin = byi * gridDim.x + bxi;
        const int cpx = nwg >> 3;
        const int sw = (lin & 7) * cpx + (lin >> 3);
        byi = sw / gridDim.x; bxi = sw - byi * gridDim.x;
    }
    const int bm = byi * BM, bn = bxi * BN;
    const ushortT* Ab = A + ob * sAo + ib * sAi + (size_t)bm * lda;
    const ushortT* Bb = Bt + ob * sBo + ib * sBi + (size_t)bn * ldb;
    const int wm = wave / WN, wn = wave - wm * WN;

    const int lrow = lane >> 2;                             // row within 16-row chunk
    const int lsw16 = ((lane & 3) ^ ((lrow >> 1) & 3)) * 8; // swizzled SRC chunk (elems)
    const int rl = lane & 15;
    const int ksw = ((lane >> 4) ^ ((rl >> 1) & 3)) << 3;   // swizzled LDS read (elems)

    f32x4 acc[4][4];
#pragma unroll
    for (int i = 0; i < 4; ++i)
#pragma unroll
        for (int j = 0; j < 4; ++j) acc[i][j] = (f32x4){0.f, 0.f, 0.f, 0.f};

    auto stage = [&](int buf, int k0) {
#pragma unroll
        for (int j = 0; j < WM; ++j) {
            int chunk = j * 4 + wave;
            gload_lds16(Ab + (size_t)(chunk * 16 + lrow) * lda + k0 + lsw16,
                        &As[buf][chunk * 512]);
        }
#pragma unroll
        for (int j = 0; j < WN; ++j) {
            int chunk = j * 4 + wave;
            gload_lds16(Bb + (size_t)(chunk * 16 + lrow) * ldb + k0 + lsw16,
                        &Bs[buf][chunk * 512]);
        }
    };

    stage(0, 0);
    __syncthreads();
    const int nt = K >> 5;
    int cur = 0;
    for (int t = 0; t < nt; ++t) {
        if (t + 1 < nt) stage(cur ^ 1, (t + 1) << 5);
        u32x4 a[4], b[4];
#pragma unroll
        for (int mf = 0; mf < 4; ++mf)
            a[mf] = *(const u32x4*)&As[cur][(wm * 64 + mf * 16 + rl) * 32 + ksw];
#pragma unroll
        for (int nf = 0; nf < 4; ++nf)
            b[nf] = *(const u32x4*)&Bs[cur][(wn * 64 + nf * 16 + rl) * 32 + ksw];
#pragma unroll
        for (int mf = 0; mf < 4; ++mf)
#pragma unroll
            for (int nf = 0; nf < 4; ++nf)
                acc[mf][nf] = mfma16(a[mf], b[nf], acc[mf][nf]);
        __syncthreads();
        cur ^= 1;
    }

    ushortT* Ch = (ushortT*)Cv + ob * sCo + ib * sCi;
#pragma unroll
    for (int nf = 0; nf < 4; ++nf) {
        int gn = bn + wn * 64 + nf * 16 + rl;
        float bv = 0.f;
        if constexpr (MODE != 4) bv = bias[gn];
#pragma unroll
        for (int mf = 0; mf < 4; ++mf) {
            int gm = bm + wm * 64 + mf * 16 + ((lane >> 4) << 2);
            if constexpr (MODE == 5) {
                const int region = gn / H;          // 0=q,1=k,2=v
                const int col = gn - region * H;
                if (region < 2) {
                    ushortT* o = (ushortT*)Cv + (size_t)region * TOKENS * H;
#pragma unroll
                    for (int r = 0; r < 4; ++r)
                        o[(size_t)(gm + r) * H + col] = f2bf(acc[mf][nf][r] + bv);
                } else {
                    u16x4 o;
#pragma unroll
                    for (int r = 0; r < 4; ++r) o[r] = f2bf(acc[mf][nf][r] + bv);
                    const int b_ = gm >> 8, s0 = gm & 255;
                    const int h_ = col >> 6, dh = col & 63;
                    *(u16x4*)((ushortT*)Cv + 2 * (size_t)TOKENS * H +
                              (((size_t)(b_ * NHD + h_) * DH + dh) << 8) + s0) = o;
                }
            } else {
#pragma unroll
                for (int r = 0; r < 4; ++r) {
                    float x = acc[mf][nf][r] + bv;
                    if constexpr (MODE == 1) x = gelu_tanh(x);
                    Ch[(size_t)(gm + r) * ldc + gn] = f2bf(x);
                }
            }
        }
    }
}

// ---------------- scale + mask + softmax on bf16 scores (in place) ----------------
__global__ __launch_bounds__(256) void attn_softmax_bf16_k(
    ushortT* __restrict__ att, const int* __restrict__ mask)
{
    int blk = blockIdx.x, tid = threadIdx.x;
    int bh = blk >> 4;
    int r0 = (blk & 15) * 16;
    int b = bh / NHD;
    int r = tid >> 4, c0 = (tid & 15) * 16;
    ushortT* rp = att + ((size_t)bh * S + r0 + r) * S;
    const int* mrow = mask + (size_t)b * S;

    u32x4 x0 = *(const u32x4*)(rp + c0);
    u32x4 x1 = *(const u32x4*)(rp + c0 + 8);
    unsigned w[8];
    *(u32x4*)&w[0] = x0; *(u32x4*)&w[4] = x1;
    float v[16];
#pragma unroll
    for (int i = 0; i < 8; ++i) {
        v[2 * i]     = bf2f((ushortT)(w[i] & 0xffffu));
        v[2 * i + 1] = bf2f((ushortT)(w[i] >> 16));
    }
#pragma unroll
    for (int j = 0; j < 16; ++j)
        v[j] = v[j] * SCALE + (mrow[c0 + j] ? 0.f : -1e9f);
    float mx = -1e30f;
#pragma unroll
    for (int j = 0; j < 16; ++j) mx = fmaxf(mx, v[j]);
#pragma unroll
    for (int m = 8; m; m >>= 1) mx = fmaxf(mx, __shfl_xor(mx, m));
    float sum = 0.f;
#pragma unroll
    for (int j = 0; j < 16; ++j) { v[j] = expf(v[j] - mx); sum += v[j]; }
#pragma unroll
    for (int m = 8; m; m >>= 1) sum += __shfl_xor(sum, m);
    float inv = 1.f / sum;
#pragma unroll
    for (int i = 0; i < 8; ++i)
        w[i] = (unsigned)f2bf(v[2 * i] * inv) |
               ((unsigned)f2bf(v[2 * i + 1] * inv) << 16);
    *(u32x4*)(rp + c0) = *(u32x4*)&w[0];
    *(u32x4*)(rp + c0 + 8) = *(u32x4*)&w[4];
}

// ---------------- all 6 weight transposes of one layer, one dispatch ----------------
__global__ __launch_bounds__(256) void transpose_all_k(
    const float* __restrict__ Wq, const float* __restrict__ Wk,
    const float* __restrict__ Wv, const float* __restrict__ Wo,
    const float* __restrict__ W1, const float* __restrict__ W2,
    ushortT* __restrict__ wtqkv, ushortT* __restrict__ wto,
    ushortT* __restrict__ wt1, ushortT* __restrict__ wt2)
{
    int idx = blockIdx.x;
    const float* W; ushortT* WT; int R, C, tr, tc;
    if (idx < 2304) {
        int mat = idx / 576, t = idx - mat * 576;
        tr = t / 24; tc = t - tr * 24; R = 768; C = 768;
        W = mat == 0 ? Wq : mat == 1 ? Wk : mat == 2 ? Wv : Wo;
        WT = mat < 3 ? wtqkv + (size_t)mat * 768 * 768 : wto;
    } else if (idx < 4608) {
        int t = idx - 2304; tr = t / 96; tc = t - tr * 96;
        R = 768; C = 3072; W = W1; WT = wt1;
    } else {
        int t = idx - 4608; tr = t / 24; tc = t - tr * 24;
        R = 3072; C = 768; W = W2; WT = wt2;
    }
    int r0 = tr * 32, c0 = tc * 32;
    __shared__ float tl[32][33];
    int trd = threadIdx.x >> 3;
    int tc4 = (threadIdx.x & 7) * 4;
    const float4 v = *(const float4*)(W + (size_t)(r0 + trd) * C + c0 + tc4);
    tl[trd][tc4 + 0] = v.x; tl[trd][tc4 + 1] = v.y;
    tl[trd][tc4 + 2] = v.z; tl[trd][tc4 + 3] = v.w;
    __syncthreads();
    u16x4 o;
#pragma unroll
    for (int q = 0; q < 4; ++q) o[q] = f2bf(tl[tc4 + q][trd]);
    *(u16x4*)(WT + (size_t)(c0 + trd) * R + r0 + tc4) = o;
}

// ---------------- pack qkv biases -> [NLAY][2304] ----------------
__global__ __launch_bounds__(256) void pack_bias_k(
    const float* __restrict__ bq, const float* __restrict__ bk,
    const float* __restrict__ bv, float* __restrict__ out)
{
    int l = blockIdx.x / 3, r = blockIdx.x - (blockIdx.x / 3) * 3;
    const float* src = r == 0 ? bq : r == 1 ? bk : bv;
#pragma unroll
    for (int j = 0; j < 3; ++j) {
        int d = threadIdx.x + 256 * j;
        out[(size_t)l * QKVN + r * H + d] = src[(size_t)l * H + d];
    }
}

// ---------------- embeddings + LN -> bf16 h; 4 tokens/block, 1 wave/token ----------------
__global__ __launch_bounds__(256) void embed_ln_k(
    const int* __restrict__ ids, const int* __restrict__ tts,
    const float* __restrict__ wemb, const float* __restrict__ pemb,
    const float* __restrict__ temb, const float* __restrict__ g,
    const float* __restrict__ bp, ushortT* __restrict__ hb)
{
    const int tok = blockIdx.x * 4 + (threadIdx.x >> 6);
    const int lane = threadIdx.x & 63;
    const int d0 = lane * 12;
    const int spos = tok & (S - 1);
    const int id = ids[tok], tt = tts[tok];
    const float* wr = wemb + (size_t)id * H + d0;
    const float* pr = pemb + (size_t)spos * H + d0;
    const float* tr = temb + (size_t)tt * H + d0;
    float x[12]; float s = 0.f, ss = 0.f;
#pragma unroll
    for (int j = 0; j < 3; ++j) {
        float4 a = *(const float4*)(wr + j * 4);
        float4 b = *(const float4*)(pr + j * 4);
        float4 c = *(const float4*)(tr + j * 4);
        float v0 = a.x + b.x + c.x, v1 = a.y + b.y + c.y;
        float v2 = a.z + b.z + c.z, v3 = a.w + b.w + c.w;
        x[j*4+0] = v0; x[j*4+1] = v1; x[j*4+2] = v2; x[j*4+3] = v3;
        s += v0 + v1 + v2 + v3;
        ss += v0*v0 + v1*v1 + v2*v2 + v3*v3;
    }
#pragma unroll
    for (int m = 32; m; m >>= 1) { s += __shfl_xor(s, m); ss += __shfl_xor(ss, m); }
    float mu = s * (1.f / H);
    float var = ss * (1.f / H) - mu * mu;
    float rs = rsqrtf(var + 1e-12f);
#pragma unroll
    for (int j = 0; j < 3; ++j) {
        float4 gv = *(const float4*)(g + d0 + j * 4);
        float4 bv = *(const float4*)(bp + d0 + j * 4);
        u16x4 o;
        o[0] = f2bf((x[j*4+0] - mu) * rs * gv.x + bv.x);
        o[1] = f2bf((x[j*4+1] - mu) * rs * gv.y + bv.y);
        o[2] = f2bf((x[j*4+2] - mu) * rs * gv.z + bv.z);
        o[3] = f2bf((x[j*4+3] - mu) * rs * gv.w + bv.w);
        *(u16x4*)(hb + (size_t)tok * H + d0 + j * 4) = o;
    }
}

// ---------------- bf16 residual add + LN, in place on hb; 4 tokens/block ----------------
__global__ __launch_bounds__(256) void add_ln_k(
    ushortT* __restrict__ hb, const ushortT* __restrict__ add,
    const float* __restrict__ g, const float* __restrict__ bp)
{
    const int tok = blockIdx.x * 4 + (threadIdx.x >> 6);
    const int lane = threadIdx.x & 63;
    const int d0 = lane * 12;
    const size_t base = (size_t)tok * H + d0;
    float x[12]; float s = 0.f, ss = 0.f;
#pragma unroll
    for (int j = 0; j < 3; ++j) {
        u16x4 hv = *(const u16x4*)(hb + base + j * 4);
        u16x4 av = *(const u16x4*)(add + base + j * 4);
#pragma unroll
        for (int q = 0; q < 4; ++q) {
            float v = bf2f(hv[q]) + bf2f(av[q]);
            x[j*4+q] = v; s += v; ss += v * v;
        }
    }
#pragma unroll
    for (int m = 32; m; m >>= 1) { s += __shfl_xor(s, m); ss += __shfl_xor(ss, m); }
    float mu = s * (1.f / H);
    float var = ss * (1.f / H) - mu * mu;
    float rs = rsqrtf(var + 1e-12f);
#pragma unroll
    for (int j = 0; j < 3; ++j) {
        float4 gv = *(const float4*)(g + d0 + j * 4);
        float4 bv = *(const float4*)(bp + d0 + j * 4);
        u16x4 o;
        o[0] = f2bf((x[j*4+0] - mu) * rs * gv.x + bv.x);
        o[1] = f2bf((x[j*4+1] - mu) * rs * gv.y + bv.y);
        o[2] = f2bf((x[j*4+2] - mu) * rs * gv.z + bv.z);
        o[3] = f2bf((x[j*4+3] - mu) * rs * gv.w + bv.w);
        *(u16x4*)(hb + base + j * 4) = o;
    }
}

// ---------------- logits + log_softmax over 9 labels (bf16 h, f32 math) ----------------
__global__ __launch_bounds__(256) void logits_k(
    const ushortT* __restrict__ hb, const float* __restrict__ fcw,
    float* __restrict__ em)
{
    int tok = blockIdx.x, tid = threadIdx.x;
    float p[LBL];
#pragma unroll
    for (int l = 0; l < LBL; ++l) p[l] = 0.f;
    const ushortT* hr = hb + (size_t)tok * H;
#pragma unroll
    for (int j = 0; j < 3; ++j) {
        int d = tid + 256 * j;
        float hv = bf2f(hr[d]);
        const float* fr = fcw + (size_t)d * LBL;
#pragma unroll
        for (int l = 0; l < LBL; ++l) p[l] = fmaf(hv, fr[l], p[l]);
    }
    __shared__ float ls[4][LBL];
    __shared__ float lg[LBL];
    __shared__ float lse;
#pragma unroll
    for (int l = 0; l < LBL; ++l) {
        float v = p[l];
#pragma unroll
        for (int m = 32; m; m >>= 1) v += __shfl_xor(v, m);
        if ((tid & 63) == 0) ls[tid >> 6][l] = v;
    }
    __syncthreads();
    if (tid < LBL) lg[tid] = ls[0][tid] + ls[1][tid] + ls[2][tid] + ls[3][tid];
    __syncthreads();
    if (tid == 0) {
        float mx = lg[0];
#pragma unroll
        for (int j = 1; j < LBL; ++j) mx = fmaxf(mx, lg[j]);
        float sm = 0.f;
#pragma unroll
        for (int j = 0; j < LBL; ++j) sm += expf(lg[j] - mx);
        lse = mx + logf(sm);
    }
    __syncthreads();
    if (tid < LBL) em[(size_t)tok * LBL + tid] = lg[tid] - lse;
}

// ---------------- CRF: one wave per batch elem, base-2 fast recursion ----------------
__global__ __launch_bounds__(64) void crf_k(
    const float* __restrict__ em, const int* __restrict__ tags,
    const int* __restrict__ mask, const float* __restrict__ sp,
    const float* __restrict__ ep, const float* __restrict__ trans,
    float* __restrict__ partial)
{
    constexpr float LOG2E = 1.4426950408889634f;
    constexpr float LN2   = 0.6931471805599453f;
    int b = blockIdx.x, t = threadIdx.x;
    __shared__ float eml[S * LBL];     // emissions * log2(e)
    __shared__ int mkl[S];
    const float* emb = em + (size_t)b * S * LBL;
    const int* tg = tags + (size_t)b * S;
    const int* mk = mask + (size_t)b * S;

    for (int i = t * 4; i < S * LBL; i += 256) {
        float4 v = *(const float4*)&emb[i];
        v.x *= LOG2E; v.y *= LOG2E; v.z *= LOG2E; v.w *= LOG2E;
        *(float4*)&eml[i] = v;
    }
    *(i32x4*)&mkl[t * 4] = *(const i32x4*)&mk[t * 4];

    int cnt = 0; float ns = 0.f;
    for (int i = t; i < S; i += 64) {
        int m = mk[i];
        cnt += (m != 0);
        if (i >= 1 && m)
            ns += trans[tg[i - 1] * LBL + tg[i]] + emb[(size_t)i * LBL + tg[i]];
    }
#pragma unroll
    for (int m = 32; m; m >>= 1) { cnt += __shfl_xor(cnt, m); ns += __shfl_xor(ns, m); }
    float num = ns + sp[tg[0]] + emb[tg[0]] + ep[tg[cnt - 1]];

    int tt = t < LBL ? t : 0;
    float trc2[LBL];
#pragma unroll
    for (int i = 0; i < LBL; ++i) trc2[i] = trans[i * LBL + tt] * LOG2E;

    __syncthreads();

    float alpha2 = (t < LBL) ? sp[t] * LOG2E + eml[t] : -1e30f;
    for (int step = 1; step < S; ++step) {
        float av[LBL];
#pragma unroll
        for (int i = 0; i < LBL; ++i) av[i] = __shfl(alpha2, i) + trc2[i];
        float mx = av[0];
#pragma unroll
        for (int i = 1; i < LBL; ++i) mx = fmaxf(mx, av[i]);
        float sm = 0.f;
#pragma unroll
        for (int i = 0; i < LBL; ++i) sm += exp2i(av[i] - mx);
        float na = mx + log2i(sm) + eml[step * LBL + tt];
        alpha2 = (mkl[step] && t < LBL) ? na : alpha2;
    }
    float z = (t < LBL) ? alpha2 + ep[t] * LOG2E : -1e30f;
    float mx = z;
#pragma unroll
    for (int m = 8; m; m >>= 1) mx = fmaxf(mx, __shfl_xor(mx, m));
    float sm = exp2i(z - mx);
#pragma unroll
    for (int m = 8; m; m >>= 1) sm += __shfl_xor(sm, m);
    if (t == 0) partial[b] = (mx + log2i(sm)) * LN2 - num;
}

__global__ void finalize_k(const float* __restrict__ partial, float* __restrict__ out) {
    float s = 0.f;
    for (int i = 0; i < BATCH; ++i) s += partial[i];
    out[0] = s;
}

__global__ void sentinel_k(float* out) { out[0] = -12345.0f; }

extern "C" void kernel_launch(void* const* d_in, const int* in_sizes, int n_in,
                              void* d_out, int out_size, void* d_ws, size_t ws_size,
                              hipStream_t stream) {
    (void)in_sizes; (void)n_in; (void)out_size;
    const int* token_ids  = (const int*)d_in[0];
    const int* token_type = (const int*)d_in[1];
    const int* amask      = (const int*)d_in[2];
    const int* y          = (const int*)d_in[3];
    const float* wemb = (const float*)d_in[4];
    const float* pemb = (const float*)d_in[5];
    const float* temb = (const float*)d_in[6];
    const float* eg   = (const float*)d_in[7];
    const float* eb   = (const float*)d_in[8];
    const float* Wq = (const float*)d_in[9];
    const float* bq = (const float*)d_in[10];
    const float* Wk = (const float*)d_in[11];
    const float* bk = (const float*)d_in[12];
    const float* Wv = (const float*)d_in[13];
    const float* bv = (const float*)d_in[14];
    const float* Wo = (const float*)d_in[15];
    const float* bo = (const float*)d_in[16];
    const float* ln1g = (const float*)d_in[17];
    const float* ln1b = (const float*)d_in[18];
    const float* W1 = (const float*)d_in[19];
    const float* b1 = (const float*)d_in[20];
    const float* W2 = (const float*)d_in[21];
    const float* b2 = (const float*)d_in[22];
    const float* ln2g = (const float*)d_in[23];
    const float* ln2b = (const float*)d_in[24];
    const float* fcw = (const float*)d_in[25];
    const float* crf_s = (const float*)d_in[26];
    const float* crf_e = (const float*)d_in[27];
    const float* crf_t = (const float*)d_in[28];

    if (ws_size < WS_FLOATS * sizeof(float)) {
        sentinel_k<<<1, 1, 0, stream>>>((float*)d_out);
        return;
    }

    float* ws = (float*)d_ws;
    ushortT* hb   = (ushortT*)(ws + HB_OFF);
    ushortT* qb   = (ushortT*)(ws + QB_OFF);   // q base; k = +TOKENS*H; vt = +2*TOKENS*H
    ushortT* kb   = (ushortT*)(ws + KB_OFF);
    ushortT* vt   = (ushortT*)(ws + VT_OFF);
    ushortT* big  = (ushortT*)(ws + BIG_OFF);
    ushortT* wtq  = (ushortT*)(ws + WTQ_OFF);  // [2304][768]
    ushortT* wto  = (ushortT*)(ws + WTO_OFF);
    ushortT* wt1  = (ushortT*)(ws + WT1_OFF);
    ushortT* wt2  = (ushortT*)(ws + WT2_OFF);
    float*   embuf = ws + EM_OFF;
    float*   part  = ws + PART_OFF;
    float*   bqkv  = ws + BQKV_OFF;

    pack_bias_k<<<NLAY * 3, 256, 0, stream>>>(bq, bk, bv, bqkv);
    embed_ln_k<<<TOKENS / 4, 256, 0, stream>>>(token_ids, token_type, wemb, pemb,
                                               temb, eg, eb, hb);

    constexpr long long HH = (long long)H * H;
    constexpr long long HF = (long long)H * FF;
    constexpr long long TOKH = (long long)S * H;        // 196608
    constexpr long long ATT_B = (long long)NHD * S * S; // 786432
    constexpr long long ATT_H = (long long)S * S;       // 65536
    constexpr long long VT_B = (long long)NHD * DH * S; // 196608
    constexpr long long VT_H = (long long)DH * S;       // 16384

    dim3 gQKV(QKVN / 128, TOKENS / 128, 1);       // 18 x 64 = 1152 (%8==0)
    dim3 gProj(H / 128, TOKENS / 128, 1);         // 6 x 64 = 384
    dim3 gFF1(FF / 128, TOKENS / 128, 1);         // 24 x 64 = 1536
    dim3 gScores(S / 128, S / 128, BATCH * NHD);  // 2 x 2 x 384
    dim3 gPV(1, 1, BATCH * NHD);                  // 256x64 tile covers head

    for (int l = 0; l < NLAY; ++l) {
        transpose_all_k<<<6912, 256, 0, stream>>>(
            Wq + l * HH, Wk + l * HH, Wv + l * HH, Wo + l * HH,
            W1 + l * HF, W2 + l * HF, wtq, wto, wt1, wt2);

        // fused q,k,v projections (2-phase 128^2 with routing epilogue)
        gemm_mfma<2,2,5><<<gQKV, 256, 0, stream>>>(
            hb, H, 0, 0, wtq, H, 0, 0, bqkv + (size_t)l * QKVN,
            qb, H, 0, 0, H, 1);

        // scores = q @ k^T  (per b,h) -> bf16
        gemm_mfma<2,2,4><<<gScores, 256, 0, stream>>>(
            qb, H, TOKH, DH, kb, H, TOKH, DH, nullptr,
            big, S, ATT_B, ATT_H, DH, NHD);

        attn_softmax_bf16_k<<<BATCH * NHD * (S / 16), 256, 0, stream>>>(big, amask);

        // ctx = probs @ v  (per b,h) -> qb as [B,S,NH,DH] bf16
        gemm_mfma<4,1,4><<<gPV, 256, 0, stream>>>(
            big, S, ATT_B, ATT_H, vt, S, VT_B, VT_H, nullptr,
            qb, H, TOKH, DH, S, NHD);

        // attention output projection -> kb (bf16)
        gemm_mfma<2,2,0><<<gProj, 256, 0, stream>>>(
            qb, H, 0, 0, wto, H, 0, 0, bo + l * H, kb, H, 0, 0, H, 1);

        add_ln_k<<<TOKENS / 4, 256, 0, stream>>>(hb, kb, ln1g + l * H, ln1b + l * H);

        // ff1 = gelu(h @ W1 + b1) -> big bf16
        gemm_mfma<2,2,1><<<gFF1, 256, 0, stream>>>(
            hb, H, 0, 0, wt1, H, 0, 0, b1 + (long long)l * FF, big, FF, 0, 0, H, 1);

        // ff2 -> qb (bf16)
        gemm_mfma<2,2,0><<<gProj, 256, 0, stream>>>(
            big, FF, 0, 0, wt2, FF, 0, 0, b2 + l * H, qb, H, 0, 0, FF, 1);

        add_ln_k<<<TOKENS / 4, 256, 0, stream>>>(hb, qb, ln2g + l * H, ln2b + l * H);
    }

    logits_k<<<TOKENS, 256, 0, stream>>>(hb, fcw, embuf);
    crf_k<<<BATCH, 64, 0, stream>>>(embuf, y, amask, crf_s, crf_e, crf_t, part);
    finalize_k<<<1, 1, 0, stream>>>(part, (float*)d_out);
}

// Round 10
// 3279.478 us; speedup vs baseline: 1.1975x; 1.0238x over previous
//
#include <hip/hip_runtime.h>
#include <math.h>

typedef unsigned short ushortT;
typedef __attribute__((ext_vector_type(4))) float f32x4;
typedef __attribute__((ext_vector_type(4))) unsigned int u32x4;
typedef __attribute__((ext_vector_type(4))) unsigned short u16x4;
typedef __attribute__((ext_vector_type(4))) int i32x4;
typedef __attribute__((ext_vector_type(8))) __bf16 bf16x8;

namespace {
constexpr int S = 256;
constexpr int H = 768;
constexpr int NLAY = 12;
constexpr int NHD = 12;
constexpr int FF = 3072;
constexpr int LBL = 9;
constexpr int DH = 64;
constexpr int BATCH = 32;
constexpr int TOKENS = BATCH * S;      // 8192
constexpr int QKVN = 3 * H;            // 2304
// softmax scale folded into exponent: p = exp2(C2*(s_raw - m_raw)), C2 = 0.125*log2(e)
constexpr float C2 = 0.18033688011112042f;

// workspace layout (float-slot units)
constexpr size_t HB_OFF  = 0;                            // h bf16 (half slots)
constexpr size_t QB_OFF  = HB_OFF + (size_t)TOKENS*H/2;  // q / ctx / ff2out bf16
constexpr size_t KB_OFF  = QB_OFF + (size_t)TOKENS*H/2;  // k / attn-out bf16
constexpr size_t VT_OFF  = KB_OFF + (size_t)TOKENS*H/2;  // v^T bf16 [B*NH*DH][S]
constexpr size_t BIG_OFF = VT_OFF + (size_t)TOKENS*H/2;  // probs bf16 == ff1 bf16
constexpr size_t WTQ_OFF = BIG_OFF + (size_t)TOKENS*FF/2;  // Wq^T,Wk^T,Wv^T contiguous
constexpr size_t WTO_OFF = WTQ_OFF + 3*(size_t)H*H/2;
constexpr size_t WT1_OFF = WTO_OFF + (size_t)H*H/2;      // W1^T [3072][768]
constexpr size_t WT2_OFF = WT1_OFF + (size_t)H*FF/2;     // W2^T [768][3072]
constexpr size_t EM_OFF  = WT2_OFF + (size_t)H*FF/2;
constexpr size_t PART_OFF= EM_OFF + (size_t)TOKENS*LBL;
constexpr size_t BQKV_OFF= PART_OFF + 64;                // packed qkv bias [12][2304]
constexpr size_t WS_FLOATS = BQKV_OFF + (size_t)NLAY*QKVN;
}

__device__ __forceinline__ ushortT f2bf(float x) {
    unsigned u = __builtin_bit_cast(unsigned, x);
    u += 0x7fffu + ((u >> 16) & 1u);
    return (ushortT)(u >> 16);
}
__device__ __forceinline__ float bf2f(ushortT h) {
    unsigned u = ((unsigned)h) << 16;
    return __builtin_bit_cast(float, u);
}

__device__ __forceinline__ float exp2i(float x) {
    float r; asm("v_exp_f32 %0, %1" : "=v"(r) : "v"(x)); return r;
}
__device__ __forceinline__ float log2i(float x) {
    float r; asm("v_log_f32 %0, %1" : "=v"(r) : "v"(x)); return r;
}

// tanh-gelu in sigmoid form: 0.5x(1+tanh(u)) == x*sigmoid(2u) == x/(1+exp2(-2u*log2e))
__device__ __forceinline__ float gelu_tanh(float x) {
    float u = 0.7978845608028654f * (x + 0.044715f * x * x * x);
    float t = exp2i(-2.8853900817779268f * u);
    return x / (1.0f + t);
}

__device__ __forceinline__ f32x4 mfma16(u32x4 a, u32x4 b, f32x4 c) {
    return __builtin_amdgcn_mfma_f32_16x16x32_bf16(
        __builtin_bit_cast(bf16x8, a), __builtin_bit_cast(bf16x8, b), c, 0, 0, 0);
}

__device__ __forceinline__ void gload_lds16(const ushortT* g, ushortT* l) {
    __builtin_amdgcn_global_load_lds(
        (const __attribute__((address_space(1))) unsigned int*)g,
        (__attribute__((address_space(3))) unsigned int*)l,
        16, 0, 0);
}

// ---------------- bf16 MFMA GEMM, double-buffered 2-phase ----------------
// C[m,n] = epi( sum_k A[m,k]*Bt[n,k] + bias[n] )
// LDS rows are 64B (32 bf16). Bank-conflict fix (T2, both-sides): 16B slot
// XOR-swizzled with (row>>1)&3, applied on the GLOBAL source chunk during
// staging (linear LDS dest, rule #21) and on the ds_read address.
// MODE: 0 = bf16 + bias | 1 = bf16 + bias + gelu | 4 = bf16, no bias
//       | 5 = fused-QKV routing (Cv = q base; k at +TOKENS*H; v^T at +2*TOKENS*H)
//       | 6 = fused mask+row-softmax (requires WM==1,WN==4 so BN==256==S spans
//             full rows; `bias` carries the int mask pointer; ob indexes batch)
// 2D grids (gridDim.z==1) get the XCD-aware block swizzle (T1); grids are %8==0.
template<int WM, int WN, int MODE>
__global__ __launch_bounds__(256) void gemm_mfma(
    const ushortT* __restrict__ A, int lda, long long sAo, long long sAi,
    const ushortT* __restrict__ Bt, int ldb, long long sBo, long long sBi,
    const float* __restrict__ bias,
    void* __restrict__ Cv, int ldc, long long sCo, long long sCi,
    int K, int innerN)
{
    constexpr int BM = WM * 64, BN = WN * 64;
    __shared__ __align__(16) ushortT As[2][BM * 32];
    __shared__ __align__(16) ushortT Bs[2][BN * 32];
    const int tid = threadIdx.x;
    const int wave = tid >> 6, lane = tid & 63;
    const int ob = blockIdx.z / innerN, ib = blockIdx.z - ob * innerN;

    int bxi = blockIdx.x, byi = blockIdx.y;
    if (gridDim.z == 1) {
        const int nwg = gridDim.x * gridDim.y;
        const int lin = byi * gridDim.x + bxi;
        const int cpx = nwg >> 3;
        const int sw = (lin & 7) * cpx + (lin >> 3);
        byi = sw / gridDim.x; bxi = sw - byi * gridDim.x;
    }
    const int bm = byi * BM, bn = bxi * BN;
    const ushortT* Ab = A + ob * sAo + ib * sAi + (size_t)bm * lda;
    const ushortT* Bb = Bt + ob * sBo + ib * sBi + (size_t)bn * ldb;
    const int wm = wave / WN, wn = wave - wm * WN;

    const int lrow = lane >> 2;                             // row within 16-row chunk
    const int lsw16 = ((lane & 3) ^ ((lrow >> 1) & 3)) * 8; // swizzled SRC chunk (elems)
    const int rl = lane & 15;
    const int kg4 = (lane >> 4) << 2;
    const int ksw = ((lane >> 4) ^ ((rl >> 1) & 3)) << 3;   // swizzled LDS read (elems)

    f32x4 acc[4][4];
#pragma unroll
    for (int i = 0; i < 4; ++i)
#pragma unroll
        for (int j = 0; j < 4; ++j) acc[i][j] = (f32x4){0.f, 0.f, 0.f, 0.f};

    auto stage = [&](int buf, int k0) {
#pragma unroll
        for (int j = 0; j < WM; ++j) {
            int chunk = j * 4 + wave;
            gload_lds16(Ab + (size_t)(chunk * 16 + lrow) * lda + k0 + lsw16,
                        &As[buf][chunk * 512]);
        }
#pragma unroll
        for (int j = 0; j < WN; ++j) {
            int chunk = j * 4 + wave;
            gload_lds16(Bb + (size_t)(chunk * 16 + lrow) * ldb + k0 + lsw16,
                        &Bs[buf][chunk * 512]);
        }
    };

    stage(0, 0);
    __syncthreads();
    const int nt = K >> 5;
    int cur = 0;
    for (int t = 0; t < nt; ++t) {
        if (t + 1 < nt) stage(cur ^ 1, (t + 1) << 5);
        u32x4 a[4], b[4];
#pragma unroll
        for (int mf = 0; mf < 4; ++mf)
            a[mf] = *(const u32x4*)&As[cur][(wm * 64 + mf * 16 + rl) * 32 + ksw];
#pragma unroll
        for (int nf = 0; nf < 4; ++nf)
            b[nf] = *(const u32x4*)&Bs[cur][(wn * 64 + nf * 16 + rl) * 32 + ksw];
#pragma unroll
        for (int mf = 0; mf < 4; ++mf)
#pragma unroll
            for (int nf = 0; nf < 4; ++nf)
                acc[mf][nf] = mfma16(a[mf], b[nf], acc[mf][nf]);
        __syncthreads();
        cur ^= 1;
    }

    ushortT* Ch = (ushortT*)Cv + ob * sCo + ib * sCi;
    if constexpr (MODE == 6) {
        // ---- fused mask + row softmax epilogue (WM=1: all waves share rows) ----
        __shared__ float red6[2][4][64];
        const int* mrow = (const int*)bias + ob * S;
        float mb[4];
#pragma unroll
        for (int nf = 0; nf < 4; ++nf)
            mb[nf] = mrow[bn + wn * 64 + nf * 16 + rl] ? 0.f : -8e9f;
        // per-row max over this wave's 64 cols
        float pm[4][4];
#pragma unroll
        for (int mf = 0; mf < 4; ++mf)
#pragma unroll
            for (int r = 0; r < 4; ++r) pm[mf][r] = -1e30f;
#pragma unroll
        for (int mf = 0; mf < 4; ++mf)
#pragma unroll
            for (int nf = 0; nf < 4; ++nf)
#pragma unroll
                for (int r = 0; r < 4; ++r) {
                    acc[mf][nf][r] += mb[nf];
                    pm[mf][r] = fmaxf(pm[mf][r], acc[mf][nf][r]);
                }
#pragma unroll
        for (int mf = 0; mf < 4; ++mf)
#pragma unroll
            for (int r = 0; r < 4; ++r) {
                float v = pm[mf][r];
                v = fmaxf(v, __shfl_xor(v, 1));
                v = fmaxf(v, __shfl_xor(v, 2));
                v = fmaxf(v, __shfl_xor(v, 4));
                v = fmaxf(v, __shfl_xor(v, 8));
                pm[mf][r] = v;
            }
        if (rl == 0) {
#pragma unroll
            for (int mf = 0; mf < 4; ++mf)
#pragma unroll
                for (int r = 0; r < 4; ++r)
                    red6[0][wn][mf * 16 + kg4 + r] = pm[mf][r];
        }
        __syncthreads();
        float Mx[4][4];
#pragma unroll
        for (int mf = 0; mf < 4; ++mf)
#pragma unroll
            for (int r = 0; r < 4; ++r) {
                const int row = mf * 16 + kg4 + r;
                Mx[mf][r] = fmaxf(fmaxf(red6[0][0][row], red6[0][1][row]),
                                  fmaxf(red6[0][2][row], red6[0][3][row]));
            }
        // exp + per-row partial sum (overwrite acc with exp'ed values)
        float ps[4][4];
#pragma unroll
        for (int mf = 0; mf < 4; ++mf)
#pragma unroll
            for (int r = 0; r < 4; ++r) ps[mf][r] = 0.f;
#pragma unroll
        for (int mf = 0; mf < 4; ++mf)
#pragma unroll
            for (int nf = 0; nf < 4; ++nf)
#pragma unroll
                for (int r = 0; r < 4; ++r) {
                    float e = exp2i(C2 * (acc[mf][nf][r] - Mx[mf][r]));
                    acc[mf][nf][r] = e;
                    ps[mf][r] += e;
                }
#pragma unroll
        for (int mf = 0; mf < 4; ++mf)
#pragma unroll
            for (int r = 0; r < 4; ++r) {
                float v = ps[mf][r];
                v += __shfl_xor(v, 1);
                v += __shfl_xor(v, 2);
                v += __shfl_xor(v, 4);
                v += __shfl_xor(v, 8);
                ps[mf][r] = v;
            }
        if (rl == 0) {
#pragma unroll
            for (int mf = 0; mf < 4; ++mf)
#pragma unroll
                for (int r = 0; r < 4; ++r)
                    red6[1][wn][mf * 16 + kg4 + r] = ps[mf][r];
        }
        __syncthreads();
#pragma unroll
        for (int mf = 0; mf < 4; ++mf) {
            float inv[4];
#pragma unroll
            for (int r = 0; r < 4; ++r) {
                const int row = mf * 16 + kg4 + r;
                inv[r] = 1.0f / (red6[1][0][row] + red6[1][1][row] +
                                 red6[1][2][row] + red6[1][3][row]);
            }
#pragma unroll
            for (int nf = 0; nf < 4; ++nf) {
                const int gn = bn + wn * 64 + nf * 16 + rl;
                const int gm = bm + mf * 16 + kg4;
#pragma unroll
                for (int r = 0; r < 4; ++r)
                    Ch[(size_t)(gm + r) * ldc + gn] = f2bf(acc[mf][nf][r] * inv[r]);
            }
        }
    } else {
#pragma unroll
        for (int nf = 0; nf < 4; ++nf) {
            int gn = bn + wn * 64 + nf * 16 + rl;
            float bv = 0.f;
            if constexpr (MODE != 4) bv = bias[gn];
#pragma unroll
            for (int mf = 0; mf < 4; ++mf) {
                int gm = bm + wm * 64 + mf * 16 + kg4;
                if constexpr (MODE == 5) {
                    const int region = gn / H;          // 0=q,1=k,2=v
                    const int col = gn - region * H;
                    if (region < 2) {
                        ushortT* o = (ushortT*)Cv + (size_t)region * TOKENS * H;
#pragma unroll
                        for (int r = 0; r < 4; ++r)
                            o[(size_t)(gm + r) * H + col] = f2bf(acc[mf][nf][r] + bv);
                    } else {
                        u16x4 o;
#pragma unroll
                        for (int r = 0; r < 4; ++r) o[r] = f2bf(acc[mf][nf][r] + bv);
                        const int b_ = gm >> 8, s0 = gm & 255;
                        const int h_ = col >> 6, dh = col & 63;
                        *(u16x4*)((ushortT*)Cv + 2 * (size_t)TOKENS * H +
                                  (((size_t)(b_ * NHD + h_) * DH + dh) << 8) + s0) = o;
                    }
                } else {
#pragma unroll
                    for (int r = 0; r < 4; ++r) {
                        float x = acc[mf][nf][r] + bv;
                        if constexpr (MODE == 1) x = gelu_tanh(x);
                        Ch[(size_t)(gm + r) * ldc + gn] = f2bf(x);
                    }
                }
            }
        }
    }
}

// ---------------- all 6 weight transposes of one layer, one dispatch ----------------
__global__ __launch_bounds__(256) void transpose_all_k(
    const float* __restrict__ Wq, const float* __restrict__ Wk,
    const float* __restrict__ Wv, const float* __restrict__ Wo,
    const float* __restrict__ W1, const float* __restrict__ W2,
    ushortT* __restrict__ wtqkv, ushortT* __restrict__ wto,
    ushortT* __restrict__ wt1, ushortT* __restrict__ wt2)
{
    int idx = blockIdx.x;
    const float* W; ushortT* WT; int R, C, tr, tc;
    if (idx < 2304) {
        int mat = idx / 576, t = idx - mat * 576;
        tr = t / 24; tc = t - tr * 24; R = 768; C = 768;
        W = mat == 0 ? Wq : mat == 1 ? Wk : mat == 2 ? Wv : Wo;
        WT = mat < 3 ? wtqkv + (size_t)mat * 768 * 768 : wto;
    } else if (idx < 4608) {
        int t = idx - 2304; tr = t / 96; tc = t - tr * 96;
        R = 768; C = 3072; W = W1; WT = wt1;
    } else {
        int t = idx - 4608; tr = t / 24; tc = t - tr * 24;
        R = 3072; C = 768; W = W2; WT = wt2;
    }
    int r0 = tr * 32, c0 = tc * 32;
    __shared__ float tl[32][33];
    int trd = threadIdx.x >> 3;
    int tc4 = (threadIdx.x & 7) * 4;
    const float4 v = *(const float4*)(W + (size_t)(r0 + trd) * C + c0 + tc4);
    tl[trd][tc4 + 0] = v.x; tl[trd][tc4 + 1] = v.y;
    tl[trd][tc4 + 2] = v.z; tl[trd][tc4 + 3] = v.w;
    __syncthreads();
    u16x4 o;
#pragma unroll
    for (int q = 0; q < 4; ++q) o[q] = f2bf(tl[tc4 + q][trd]);
    *(u16x4*)(WT + (size_t)(c0 + trd) * R + r0 + tc4) = o;
}

// ---------------- pack qkv biases -> [NLAY][2304] ----------------
__global__ __launch_bounds__(256) void pack_bias_k(
    const float* __restrict__ bq, const float* __restrict__ bk,
    const float* __restrict__ bv, float* __restrict__ out)
{
    int l = blockIdx.x / 3, r = blockIdx.x - (blockIdx.x / 3) * 3;
    const float* src = r == 0 ? bq : r == 1 ? bk : bv;
#pragma unroll
    for (int j = 0; j < 3; ++j) {
        int d = threadIdx.x + 256 * j;
        out[(size_t)l * QKVN + r * H + d] = src[(size_t)l * H + d];
    }
}

// ---------------- embeddings + LN -> bf16 h; 4 tokens/block, 1 wave/token ----------------
__global__ __launch_bounds__(256) void embed_ln_k(
    const int* __restrict__ ids, const int* __restrict__ tts,
    const float* __restrict__ wemb, const float* __restrict__ pemb,
    const float* __restrict__ temb, const float* __restrict__ g,
    const float* __restrict__ bp, ushortT* __restrict__ hb)
{
    const int tok = blockIdx.x * 4 + (threadIdx.x >> 6);
    const int lane = threadIdx.x & 63;
    const int d0 = lane * 12;
    const int spos = tok & (S - 1);
    const int id = ids[tok], tt = tts[tok];
    const float* wr = wemb + (size_t)id * H + d0;
    const float* pr = pemb + (size_t)spos * H + d0;
    const float* tr = temb + (size_t)tt * H + d0;
    float x[12]; float s = 0.f, ss = 0.f;
#pragma unroll
    for (int j = 0; j < 3; ++j) {
        float4 a = *(const float4*)(wr + j * 4);
        float4 b = *(const float4*)(pr + j * 4);
        float4 c = *(const float4*)(tr + j * 4);
        float v0 = a.x + b.x + c.x, v1 = a.y + b.y + c.y;
        float v2 = a.z + b.z + c.z, v3 = a.w + b.w + c.w;
        x[j*4+0] = v0; x[j*4+1] = v1; x[j*4+2] = v2; x[j*4+3] = v3;
        s += v0 + v1 + v2 + v3;
        ss += v0*v0 + v1*v1 + v2*v2 + v3*v3;
    }
#pragma unroll
    for (int m = 32; m; m >>= 1) { s += __shfl_xor(s, m); ss += __shfl_xor(ss, m); }
    float mu = s * (1.f / H);
    float var = ss * (1.f / H) - mu * mu;
    float rs = rsqrtf(var + 1e-12f);
#pragma unroll
    for (int j = 0; j < 3; ++j) {
        float4 gv = *(const float4*)(g + d0 + j * 4);
        float4 bv = *(const float4*)(bp + d0 + j * 4);
        u16x4 o;
        o[0] = f2bf((x[j*4+0] - mu) * rs * gv.x + bv.x);
        o[1] = f2bf((x[j*4+1] - mu) * rs * gv.y + bv.y);
        o[2] = f2bf((x[j*4+2] - mu) * rs * gv.z + bv.z);
        o[3] = f2bf((x[j*4+3] - mu) * rs * gv.w + bv.w);
        *(u16x4*)(hb + (size_t)tok * H + d0 + j * 4) = o;
    }
}

// ---------------- bf16 residual add + LN, in place on hb; 4 tokens/block ----------------
__global__ __launch_bounds__(256) void add_ln_k(
    ushortT* __restrict__ hb, const ushortT* __restrict__ add,
    const float* __restrict__ g, const float* __restrict__ bp)
{
    const int tok = blockIdx.x * 4 + (threadIdx.x >> 6);
    const int lane = threadIdx.x & 63;
    const int d0 = lane * 12;
    const size_t base = (size_t)tok * H + d0;
    float x[12]; float s = 0.f, ss = 0.f;
#pragma unroll
    for (int j = 0; j < 3; ++j) {
        u16x4 hv = *(const u16x4*)(hb + base + j * 4);
        u16x4 av = *(const u16x4*)(add + base + j * 4);
#pragma unroll
        for (int q = 0; q < 4; ++q) {
            float v = bf2f(hv[q]) + bf2f(av[q]);
            x[j*4+q] = v; s += v; ss += v * v;
        }
    }
#pragma unroll
    for (int m = 32; m; m >>= 1) { s += __shfl_xor(s, m); ss += __shfl_xor(ss, m); }
    float mu = s * (1.f / H);
    float var = ss * (1.f / H) - mu * mu;
    float rs = rsqrtf(var + 1e-12f);
#pragma unroll
    for (int j = 0; j < 3; ++j) {
        float4 gv = *(const float4*)(g + d0 + j * 4);
        float4 bv = *(const float4*)(bp + d0 + j * 4);
        u16x4 o;
        o[0] = f2bf((x[j*4+0] - mu) * rs * gv.x + bv.x);
        o[1] = f2bf((x[j*4+1] - mu) * rs * gv.y + bv.y);
        o[2] = f2bf((x[j*4+2] - mu) * rs * gv.z + bv.z);
        o[3] = f2bf((x[j*4+3] - mu) * rs * gv.w + bv.w);
        *(u16x4*)(hb + base + j * 4) = o;
    }
}

// ---------------- logits + log_softmax over 9 labels (bf16 h, f32 math) ----------------
__global__ __launch_bounds__(256) void logits_k(
    const ushortT* __restrict__ hb, const float* __restrict__ fcw,
    float* __restrict__ em)
{
    int tok = blockIdx.x, tid = threadIdx.x;
    float p[LBL];
#pragma unroll
    for (int l = 0; l < LBL; ++l) p[l] = 0.f;
    const ushortT* hr = hb + (size_t)tok * H;
#pragma unroll
    for (int j = 0; j < 3; ++j) {
        int d = tid + 256 * j;
        float hv = bf2f(hr[d]);
        const float* fr = fcw + (size_t)d * LBL;
#pragma unroll
        for (int l = 0; l < LBL; ++l) p[l] = fmaf(hv, fr[l], p[l]);
    }
    __shared__ float ls[4][LBL];
    __shared__ float lg[LBL];
    __shared__ float lse;
#pragma unroll
    for (int l = 0; l < LBL; ++l) {
        float v = p[l];
#pragma unroll
        for (int m = 32; m; m >>= 1) v += __shfl_xor(v, m);
        if ((tid & 63) == 0) ls[tid >> 6][l] = v;
    }
    __syncthreads();
    if (tid < LBL) lg[tid] = ls[0][tid] + ls[1][tid] + ls[2][tid] + ls[3][tid];
    __syncthreads();
    if (tid == 0) {
        float mx = lg[0];
#pragma unroll
        for (int j = 1; j < LBL; ++j) mx = fmaxf(mx, lg[j]);
        float sm = 0.f;
#pragma unroll
        for (int j = 0; j < LBL; ++j) sm += expf(lg[j] - mx);
        lse = mx + logf(sm);
    }
    __syncthreads();
    if (tid < LBL) em[(size_t)tok * LBL + tid] = lg[tid] - lse;
}

// ---------------- CRF: one wave per batch elem, base-2 fast recursion ----------------
__global__ __launch_bounds__(64) void crf_k(
    const float* __restrict__ em, const int* __restrict__ tags,
    const int* __restrict__ mask, const float* __restrict__ sp,
    const float* __restrict__ ep, const float* __restrict__ trans,
    float* __restrict__ partial)
{
    constexpr float LOG2E = 1.4426950408889634f;
    constexpr float LN2   = 0.6931471805599453f;
    int b = blockIdx.x, t = threadIdx.x;
    __shared__ float eml[S * LBL];     // emissions * log2(e)
    __shared__ int mkl[S];
    const float* emb = em + (size_t)b * S * LBL;
    const int* tg = tags + (size_t)b * S;
    const int* mk = mask + (size_t)b * S;

    for (int i = t * 4; i < S * LBL; i += 256) {
        float4 v = *(const float4*)&emb[i];
        v.x *= LOG2E; v.y *= LOG2E; v.z *= LOG2E; v.w *= LOG2E;
        *(float4*)&eml[i] = v;
    }
    *(i32x4*)&mkl[t * 4] = *(const i32x4*)&mk[t * 4];

    int cnt = 0; float ns = 0.f;
    for (int i = t; i < S; i += 64) {
        int m = mk[i];
        cnt += (m != 0);
        if (i >= 1 && m)
            ns += trans[tg[i - 1] * LBL + tg[i]] + emb[(size_t)i * LBL + tg[i]];
    }
#pragma unroll
    for (int m = 32; m; m >>= 1) { cnt += __shfl_xor(cnt, m); ns += __shfl_xor(ns, m); }
    float num = ns + sp[tg[0]] + emb[tg[0]] + ep[tg[cnt - 1]];

    int tt = t < LBL ? t : 0;
    float trc2[LBL];
#pragma unroll
    for (int i = 0; i < LBL; ++i) trc2[i] = trans[i * LBL + tt] * LOG2E;

    __syncthreads();

    float alpha2 = (t < LBL) ? sp[t] * LOG2E + eml[t] : -1e30f;
    for (int step = 1; step < S; ++step) {
        float av[LBL];
#pragma unroll
        for (int i = 0; i < LBL; ++i) av[i] = __shfl(alpha2, i) + trc2[i];
        float mx = av[0];
#pragma unroll
        for (int i = 1; i < LBL; ++i) mx = fmaxf(mx, av[i]);
        float sm = 0.f;
#pragma unroll
        for (int i = 0; i < LBL; ++i) sm += exp2i(av[i] - mx);
        float na = mx + log2i(sm) + eml[step * LBL + tt];
        alpha2 = (mkl[step] && t < LBL) ? na : alpha2;
    }
    float z = (t < LBL) ? alpha2 + ep[t] * LOG2E : -1e30f;
    float mx = z;
#pragma unroll
    for (int m = 8; m; m >>= 1) mx = fmaxf(mx, __shfl_xor(mx, m));
    float sm = exp2i(z - mx);
#pragma unroll
    for (int m = 8; m; m >>= 1) sm += __shfl_xor(sm, m);
    if (t == 0) partial[b] = (mx + log2i(sm)) * LN2 - num;
}

__global__ void finalize_k(const float* __restrict__ partial, float* __restrict__ out) {
    float s = 0.f;
    for (int i = 0; i < BATCH; ++i) s += partial[i];
    out[0] = s;
}

__global__ void sentinel_k(float* out) { out[0] = -12345.0f; }

extern "C" void kernel_launch(void* const* d_in, const int* in_sizes, int n_in,
                              void* d_out, int out_size, void* d_ws, size_t ws_size,
                              hipStream_t stream) {
    (void)in_sizes; (void)n_in; (void)out_size;
    const int* token_ids  = (const int*)d_in[0];
    const int* token_type = (const int*)d_in[1];
    const int* amask      = (const int*)d_in[2];
    const int* y          = (const int*)d_in[3];
    const float* wemb = (const float*)d_in[4];
    const float* pemb = (const float*)d_in[5];
    const float* temb = (const float*)d_in[6];
    const float* eg   = (const float*)d_in[7];
    const float* eb   = (const float*)d_in[8];
    const float* Wq = (const float*)d_in[9];
    const float* bq = (const float*)d_in[10];
    const float* Wk = (const float*)d_in[11];
    const float* bk = (const float*)d_in[12];
    const float* Wv = (const float*)d_in[13];
    const float* bv = (const float*)d_in[14];
    const float* Wo = (const float*)d_in[15];
    const float* bo = (const float*)d_in[16];
    const float* ln1g = (const float*)d_in[17];
    const float* ln1b = (const float*)d_in[18];
    const float* W1 = (const float*)d_in[19];
    const float* b1 = (const float*)d_in[20];
    const float* W2 = (const float*)d_in[21];
    const float* b2 = (const float*)d_in[22];
    const float* ln2g = (const float*)d_in[23];
    const float* ln2b = (const float*)d_in[24];
    const float* fcw = (const float*)d_in[25];
    const float* crf_s = (const float*)d_in[26];
    const float* crf_e = (const float*)d_in[27];
    const float* crf_t = (const float*)d_in[28];

    if (ws_size < WS_FLOATS * sizeof(float)) {
        sentinel_k<<<1, 1, 0, stream>>>((float*)d_out);
        return;
    }

    float* ws = (float*)d_ws;
    ushortT* hb   = (ushortT*)(ws + HB_OFF);
    ushortT* qb   = (ushortT*)(ws + QB_OFF);   // q base; k = +TOKENS*H; vt = +2*TOKENS*H
    ushortT* kb   = (ushortT*)(ws + KB_OFF);
    ushortT* vt   = (ushortT*)(ws + VT_OFF);
    ushortT* big  = (ushortT*)(ws + BIG_OFF);
    ushortT* wtq  = (ushortT*)(ws + WTQ_OFF);  // [2304][768]
    ushortT* wto  = (ushortT*)(ws + WTO_OFF);
    ushortT* wt1  = (ushortT*)(ws + WT1_OFF);
    ushortT* wt2  = (ushortT*)(ws + WT2_OFF);
    float*   embuf = ws + EM_OFF;
    float*   part  = ws + PART_OFF;
    float*   bqkv  = ws + BQKV_OFF;

    pack_bias_k<<<NLAY * 3, 256, 0, stream>>>(bq, bk, bv, bqkv);
    embed_ln_k<<<TOKENS / 4, 256, 0, stream>>>(token_ids, token_type, wemb, pemb,
                                               temb, eg, eb, hb);

    constexpr long long HH = (long long)H * H;
    constexpr long long HF = (long long)H * FF;
    constexpr long long TOKH = (long long)S * H;        // 196608
    constexpr long long ATT_B = (long long)NHD * S * S; // 786432
    constexpr long long ATT_H = (long long)S * S;       // 65536
    constexpr long long VT_B = (long long)NHD * DH * S; // 196608
    constexpr long long VT_H = (long long)DH * S;       // 16384

    dim3 gQKV(QKVN / 128, TOKENS / 128, 1);       // 18 x 64 = 1152 (%8==0)
    dim3 gProj(H / 128, TOKENS / 128, 1);         // 6 x 64 = 384
    dim3 gFF1(FF / 128, TOKENS / 128, 1);         // 24 x 64 = 1536
    dim3 gScores(1, S / 64, BATCH * NHD);         // (N/256, M/64, 384) = 1x4x384
    dim3 gPV(1, 1, BATCH * NHD);                  // 256x64 tile covers head

    for (int l = 0; l < NLAY; ++l) {
        transpose_all_k<<<6912, 256, 0, stream>>>(
            Wq + l * HH, Wk + l * HH, Wv + l * HH, Wo + l * HH,
            W1 + l * HF, W2 + l * HF, wtq, wto, wt1, wt2);

        // fused q,k,v projections (2-phase 128^2 with routing epilogue)
        gemm_mfma<2,2,5><<<gQKV, 256, 0, stream>>>(
            hb, H, 0, 0, wtq, H, 0, 0, bqkv + (size_t)l * QKVN,
            qb, H, 0, 0, H, 1);

        // probs = softmax(mask(q @ k^T)) per (b,h), fused epilogue -> bf16
        gemm_mfma<1,4,6><<<gScores, 256, 0, stream>>>(
            qb, H, TOKH, DH, kb, H, TOKH, DH, (const float*)amask,
            big, S, ATT_B, ATT_H, DH, NHD);

        // ctx = probs @ v  (per b,h) -> qb as [B,S,NH,DH] bf16
        gemm_mfma<4,1,4><<<gPV, 256, 0, stream>>>(
            big, S, ATT_B, ATT_H, vt, S, VT_B, VT_H, nullptr,
            qb, H, TOKH, DH, S, NHD);

        // attention output projection -> kb (bf16)
        gemm_mfma<2,2,0><<<gProj, 256, 0, stream>>>(
            qb, H, 0, 0, wto, H, 0, 0, bo + l * H, kb, H, 0, 0, H, 1);

        add_ln_k<<<TOKENS / 4, 256, 0, stream>>>(hb, kb, ln1g + l * H, ln1b + l * H);

        // ff1 = gelu(h @ W1 + b1) -> big bf16
        gemm_mfma<2,2,1><<<gFF1, 256, 0, stream>>>(
            hb, H, 0, 0, wt1, H, 0, 0, b1 + (long long)l * FF, big, FF, 0, 0, H, 1);

        // ff2 -> qb (bf16)
        gemm_mfma<2,2,0><<<gProj, 256, 0, stream>>>(
            big, FF, 0, 0, wt2, FF, 0, 0, b2 + l * H, qb, H, 0, 0, FF, 1);

        add_ln_k<<<TOKENS / 4, 256, 0, stream>>>(hb, qb, ln2g + l * H, ln2b + l * H);
    }

    logits_k<<<TOKENS, 256, 0, stream>>>(hb, fcw, embuf);
    crf_k<<<BATCH, 64, 0, stream>>>(embuf, y, amask, crf_s, crf_e, crf_t, part);
    finalize_k<<<1, 1, 0, stream>>>(part, (float*)d_out);
}

// Round 12
// 3070.680 us; speedup vs baseline: 1.2789x; 1.0680x over previous
//
#include <hip/hip_runtime.h>
#include <math.h>

typedef unsigned short ushortT;
typedef __attribute__((ext_vector_type(4))) float f32x4;
typedef __attribute__((ext_vector_type(4))) unsigned int u32x4;
typedef __attribute__((ext_vector_type(4))) unsigned short u16x4;
typedef __attribute__((ext_vector_type(4))) int i32x4;
typedef __attribute__((ext_vector_type(8))) __bf16 bf16x8;

namespace {
constexpr int S = 256;
constexpr int H = 768;
constexpr int NLAY = 12;
constexpr int NHD = 12;
constexpr int FF = 3072;
constexpr int LBL = 9;
constexpr int DH = 64;
constexpr int BATCH = 32;
constexpr int TOKENS = BATCH * S;      // 8192
constexpr int QKVN = 3 * H;            // 2304
// softmax scale folded into exponent: p = exp2(C2*(s_raw - m_raw)), C2 = 0.125*log2(e)
constexpr float C2 = 0.18033688011112042f;

// workspace layout (float-slot units)
constexpr size_t HB_OFF  = 0;                            // h bf16 (half slots)
constexpr size_t QB_OFF  = HB_OFF + (size_t)TOKENS*H/2;  // q / ctx / ff2out bf16
constexpr size_t KB_OFF  = QB_OFF + (size_t)TOKENS*H/2;  // k / attn-out bf16
constexpr size_t VT_OFF  = KB_OFF + (size_t)TOKENS*H/2;  // v^T bf16 [B*NH*DH][S]
constexpr size_t BIG_OFF = VT_OFF + (size_t)TOKENS*H/2;  // probs bf16 == ff1 bf16
constexpr size_t WTQ_OFF = BIG_OFF + (size_t)TOKENS*FF/2;  // Wq^T,Wk^T,Wv^T contiguous
constexpr size_t WTO_OFF = WTQ_OFF + 3*(size_t)H*H/2;
constexpr size_t WT1_OFF = WTO_OFF + (size_t)H*H/2;      // W1^T [3072][768]
constexpr size_t WT2_OFF = WT1_OFF + (size_t)H*FF/2;     // W2^T [768][3072]
constexpr size_t EM_OFF  = WT2_OFF + (size_t)H*FF/2;
constexpr size_t PART_OFF= EM_OFF + (size_t)TOKENS*LBL;
constexpr size_t BQKV_OFF= PART_OFF + 64;                // packed qkv bias [12][2304]
constexpr size_t WS_FLOATS = BQKV_OFF + (size_t)NLAY*QKVN;
}

__device__ __forceinline__ ushortT f2bf(float x) {
    unsigned u = __builtin_bit_cast(unsigned, x);
    u += 0x7fffu + ((u >> 16) & 1u);
    return (ushortT)(u >> 16);
}
__device__ __forceinline__ float bf2f(ushortT h) {
    unsigned u = ((unsigned)h) << 16;
    return __builtin_bit_cast(float, u);
}

__device__ __forceinline__ float exp2i(float x) {
    float r; asm("v_exp_f32 %0, %1" : "=v"(r) : "v"(x)); return r;
}
__device__ __forceinline__ float log2i(float x) {
    float r; asm("v_log_f32 %0, %1" : "=v"(r) : "v"(x)); return r;
}

// tanh-gelu in sigmoid form: 0.5x(1+tanh(u)) == x*sigmoid(2u) == x/(1+exp2(-2u*log2e))
__device__ __forceinline__ float gelu_tanh(float x) {
    float u = 0.7978845608028654f * (x + 0.044715f * x * x * x);
    float t = exp2i(-2.8853900817779268f * u);
    return x / (1.0f + t);
}

__device__ __forceinline__ f32x4 mfma16(u32x4 a, u32x4 b, f32x4 c) {
    return __builtin_amdgcn_mfma_f32_16x16x32_bf16(
        __builtin_bit_cast(bf16x8, a), __builtin_bit_cast(bf16x8, b), c, 0, 0, 0);
}

__device__ __forceinline__ void gload_lds16(const ushortT* g, ushortT* l) {
    __builtin_amdgcn_global_load_lds(
        (const __attribute__((address_space(1))) unsigned int*)g,
        (__attribute__((address_space(3))) unsigned int*)l,
        16, 0, 0);
}

// ---------------- bf16 MFMA GEMM, 3-buffer counted-vmcnt pipeline ----------------
// C[m,n] = epi( sum_k A[m,k]*Bt[n,k] + bias[n] )
// K-loop (T3/T4 minimal form): 3 LDS buffers; per iter t:
//   { vmcnt(WM+WN); s_barrier; ds_read buf[t%3]; stage tile t+2; MFMA }.
// FIFO invariant (R11-bug fix): each wave's stage() issues exactly WM+WN loads
// (A: WM, B: WN) — so vmcnt(WM+WN) permits ONE group (tile t+1) outstanding and
// certifies tile t's group landed. [R11 used vmcnt(8) = TWO groups at <2,2> →
// tile t readable before landing → intermittent NaN.] Barrier then publishes
// all waves' tile-t writes. Tail iters re-stage the last tile into the dead
// buffer so the one-group-per-iter count stays exact.
// LDS rows are 64B (32 bf16); bank-conflict fix (T2, both-sides): 16B slot
// XOR-swizzled with (row>>1)&3 on the GLOBAL source chunk and the ds_read.
// MODE: 0 = bf16 + bias | 1 = bf16 + bias + gelu | 4 = bf16, no bias
//       | 5 = fused-QKV routing (Cv = q base; k at +TOKENS*H; v^T at +2*TOKENS*H)
//       | 6 = fused mask+row-softmax (WM==1,WN==4, BN==256==S spans full rows;
//             `bias` carries the int mask pointer; ob indexes batch)
// 2D grids (gridDim.z==1) get the XCD-aware block swizzle (T1); grids are %8==0.
template<int WM, int WN, int MODE>
__global__ __launch_bounds__(256) void gemm_mfma(
    const ushortT* __restrict__ A, int lda, long long sAo, long long sAi,
    const ushortT* __restrict__ Bt, int ldb, long long sBo, long long sBi,
    const float* __restrict__ bias,
    void* __restrict__ Cv, int ldc, long long sCo, long long sCi,
    int K, int innerN)
{
    constexpr int BM = WM * 64, BN = WN * 64;
    __shared__ __align__(16) ushortT As[3][BM * 32];
    __shared__ __align__(16) ushortT Bs[3][BN * 32];
    const int tid = threadIdx.x;
    const int wave = tid >> 6, lane = tid & 63;
    const int ob = blockIdx.z / innerN, ib = blockIdx.z - ob * innerN;

    int bxi = blockIdx.x, byi = blockIdx.y;
    if (gridDim.z == 1) {
        const int nwg = gridDim.x * gridDim.y;
        const int lin = byi * gridDim.x + bxi;
        const int cpx = nwg >> 3;
        const int sw = (lin & 7) * cpx + (lin >> 3);
        byi = sw / gridDim.x; bxi = sw - byi * gridDim.x;
    }
    const int bm = byi * BM, bn = bxi * BN;
    const ushortT* Ab = A + ob * sAo + ib * sAi + (size_t)bm * lda;
    const ushortT* Bb = Bt + ob * sBo + ib * sBi + (size_t)bn * ldb;
    const int wm = wave / WN, wn = wave - wm * WN;

    const int lrow = lane >> 2;                             // row within 16-row chunk
    const int lsw16 = ((lane & 3) ^ ((lrow >> 1) & 3)) * 8; // swizzled SRC chunk (elems)
    const int rl = lane & 15;
    const int kg4 = (lane >> 4) << 2;
    const int ksw = ((lane >> 4) ^ ((rl >> 1) & 3)) << 3;   // swizzled LDS read (elems)

    f32x4 acc[4][4];
#pragma unroll
    for (int i = 0; i < 4; ++i)
#pragma unroll
        for (int j = 0; j < 4; ++j) acc[i][j] = (f32x4){0.f, 0.f, 0.f, 0.f};

    auto stage = [&](int buf, int k0) {
#pragma unroll
        for (int j = 0; j < WM; ++j) {
            int chunk = j * 4 + wave;
            gload_lds16(Ab + (size_t)(chunk * 16 + lrow) * lda + k0 + lsw16,
                        &As[buf][chunk * 512]);
        }
#pragma unroll
        for (int j = 0; j < WN; ++j) {
            int chunk = j * 4 + wave;
            gload_lds16(Bb + (size_t)(chunk * 16 + lrow) * ldb + k0 + lsw16,
                        &Bs[buf][chunk * 512]);
        }
    };

    const int nt = K >> 5;
    stage(0, 0);
    stage(1, ((nt > 1) ? 1 : 0) << 5);
    int cur = 0;
    for (int t = 0; t < nt; ++t) {
        // wait: own tile-t group landed (one group of WM+WN loads may remain)
        if constexpr (WM + WN == 4)
            asm volatile("s_waitcnt vmcnt(4)" ::: "memory");
        else
            asm volatile("s_waitcnt vmcnt(5)" ::: "memory");
        __builtin_amdgcn_s_barrier();                      // publish tile-t across waves
        __builtin_amdgcn_sched_barrier(0);
        u32x4 a[4], b[4];
#pragma unroll
        for (int mf = 0; mf < 4; ++mf)
            a[mf] = *(const u32x4*)&As[cur][(wm * 64 + mf * 16 + rl) * 32 + ksw];
#pragma unroll
        for (int nf = 0; nf < 4; ++nf)
            b[nf] = *(const u32x4*)&Bs[cur][(wn * 64 + nf * 16 + rl) * 32 + ksw];
        {   // stage tile t+2 (clamped re-stage at tail keeps FIFO count exact)
            const int nx = (t + 2 < nt) ? t + 2 : nt - 1;
            int nb = cur + 2; if (nb >= 3) nb -= 3;
            stage(nb, nx << 5);
        }
#pragma unroll
        for (int mf = 0; mf < 4; ++mf)
#pragma unroll
            for (int nf = 0; nf < 4; ++nf)
                acc[mf][nf] = mfma16(a[mf], b[nf], acc[mf][nf]);
        cur = (cur + 1 == 3) ? 0 : cur + 1;
    }
    asm volatile("s_waitcnt vmcnt(0)" ::: "memory");       // drain clamped stages

    ushortT* Ch = (ushortT*)Cv + ob * sCo + ib * sCi;
    if constexpr (MODE == 6) {
        // ---- fused mask + row softmax epilogue (WM=1: all waves share rows) ----
        __shared__ float red6[2][4][64];
        const int* mrow = (const int*)bias + ob * S;
        float mb[4];
#pragma unroll
        for (int nf = 0; nf < 4; ++nf)
            mb[nf] = mrow[bn + wn * 64 + nf * 16 + rl] ? 0.f : -8e9f;
        float pm[4][4];
#pragma unroll
        for (int mf = 0; mf < 4; ++mf)
#pragma unroll
            for (int r = 0; r < 4; ++r) pm[mf][r] = -1e30f;
#pragma unroll
        for (int mf = 0; mf < 4; ++mf)
#pragma unroll
            for (int nf = 0; nf < 4; ++nf)
#pragma unroll
                for (int r = 0; r < 4; ++r) {
                    acc[mf][nf][r] += mb[nf];
                    pm[mf][r] = fmaxf(pm[mf][r], acc[mf][nf][r]);
                }
#pragma unroll
        for (int mf = 0; mf < 4; ++mf)
#pragma unroll
            for (int r = 0; r < 4; ++r) {
                float v = pm[mf][r];
                v = fmaxf(v, __shfl_xor(v, 1));
                v = fmaxf(v, __shfl_xor(v, 2));
                v = fmaxf(v, __shfl_xor(v, 4));
                v = fmaxf(v, __shfl_xor(v, 8));
                pm[mf][r] = v;
            }
        if (rl == 0) {
#pragma unroll
            for (int mf = 0; mf < 4; ++mf)
#pragma unroll
                for (int r = 0; r < 4; ++r)
                    red6[0][wn][mf * 16 + kg4 + r] = pm[mf][r];
        }
        __syncthreads();
        float Mx[4][4];
#pragma unroll
        for (int mf = 0; mf < 4; ++mf)
#pragma unroll
            for (int r = 0; r < 4; ++r) {
                const int row = mf * 16 + kg4 + r;
                Mx[mf][r] = fmaxf(fmaxf(red6[0][0][row], red6[0][1][row]),
                                  fmaxf(red6[0][2][row], red6[0][3][row]));
            }
        float ps[4][4];
#pragma unroll
        for (int mf = 0; mf < 4; ++mf)
#pragma unroll
            for (int r = 0; r < 4; ++r) ps[mf][r] = 0.f;
#pragma unroll
        for (int mf = 0; mf < 4; ++mf)
#pragma unroll
            for (int nf = 0; nf < 4; ++nf)
#pragma unroll
                for (int r = 0; r < 4; ++r) {
                    float e = exp2i(C2 * (acc[mf][nf][r] - Mx[mf][r]));
                    acc[mf][nf][r] = e;
                    ps[mf][r] += e;
                }
#pragma unroll
        for (int mf = 0; mf < 4; ++mf)
#pragma unroll
            for (int r = 0; r < 4; ++r) {
                float v = ps[mf][r];
                v += __shfl_xor(v, 1);
                v += __shfl_xor(v, 2);
                v += __shfl_xor(v, 4);
                v += __shfl_xor(v, 8);
                ps[mf][r] = v;
            }
        if (rl == 0) {
#pragma unroll
            for (int mf = 0; mf < 4; ++mf)
#pragma unroll
                for (int r = 0; r < 4; ++r)
                    red6[1][wn][mf * 16 + kg4 + r] = ps[mf][r];
        }
        __syncthreads();
#pragma unroll
        for (int mf = 0; mf < 4; ++mf) {
            float inv[4];
#pragma unroll
            for (int r = 0; r < 4; ++r) {
                const int row = mf * 16 + kg4 + r;
                inv[r] = 1.0f / (red6[1][0][row] + red6[1][1][row] +
                                 red6[1][2][row] + red6[1][3][row]);
            }
#pragma unroll
            for (int nf = 0; nf < 4; ++nf) {
                const int gn = bn + wn * 64 + nf * 16 + rl;
                const int gm = bm + mf * 16 + kg4;
#pragma unroll
                for (int r = 0; r < 4; ++r)
                    Ch[(size_t)(gm + r) * ldc + gn] = f2bf(acc[mf][nf][r] * inv[r]);
            }
        }
    } else {
#pragma unroll
        for (int nf = 0; nf < 4; ++nf) {
            int gn = bn + wn * 64 + nf * 16 + rl;
            float bv = 0.f;
            if constexpr (MODE != 4) bv = bias[gn];
#pragma unroll
            for (int mf = 0; mf < 4; ++mf) {
                int gm = bm + wm * 64 + mf * 16 + kg4;
                if constexpr (MODE == 5) {
                    const int region = gn / H;          // 0=q,1=k,2=v
                    const int col = gn - region * H;
                    if (region < 2) {
                        ushortT* o = (ushortT*)Cv + (size_t)region * TOKENS * H;
#pragma unroll
                        for (int r = 0; r < 4; ++r)
                            o[(size_t)(gm + r) * H + col] = f2bf(acc[mf][nf][r] + bv);
                    } else {
                        u16x4 o;
#pragma unroll
                        for (int r = 0; r < 4; ++r) o[r] = f2bf(acc[mf][nf][r] + bv);
                        const int b_ = gm >> 8, s0 = gm & 255;
                        const int h_ = col >> 6, dh = col & 63;
                        *(u16x4*)((ushortT*)Cv + 2 * (size_t)TOKENS * H +
                                  (((size_t)(b_ * NHD + h_) * DH + dh) << 8) + s0) = o;
                    }
                } else {
#pragma unroll
                    for (int r = 0; r < 4; ++r) {
                        float x = acc[mf][nf][r] + bv;
                        if constexpr (MODE == 1) x = gelu_tanh(x);
                        Ch[(size_t)(gm + r) * ldc + gn] = f2bf(x);
                    }
                }
            }
        }
    }
}

// ---------------- all 6 weight transposes of one layer, one dispatch ----------------
__global__ __launch_bounds__(256) void transpose_all_k(
    const float* __restrict__ Wq, const float* __restrict__ Wk,
    const float* __restrict__ Wv, const float* __restrict__ Wo,
    const float* __restrict__ W1, const float* __restrict__ W2,
    ushortT* __restrict__ wtqkv, ushortT* __restrict__ wto,
    ushortT* __restrict__ wt1, ushortT* __restrict__ wt2)
{
    int idx = blockIdx.x;
    const float* W; ushortT* WT; int R, C, tr, tc;
    if (idx < 2304) {
        int mat = idx / 576, t = idx - mat * 576;
        tr = t / 24; tc = t - tr * 24; R = 768; C = 768;
        W = mat == 0 ? Wq : mat == 1 ? Wk : mat == 2 ? Wv : Wo;
        WT = mat < 3 ? wtqkv + (size_t)mat * 768 * 768 : wto;
    } else if (idx < 4608) {
        int t = idx - 2304; tr = t / 96; tc = t - tr * 96;
        R = 768; C = 3072; W = W1; WT = wt1;
    } else {
        int t = idx - 4608; tr = t / 24; tc = t - tr * 24;
        R = 3072; C = 768; W = W2; WT = wt2;
    }
    int r0 = tr * 32, c0 = tc * 32;
    __shared__ float tl[32][33];
    int trd = threadIdx.x >> 3;
    int tc4 = (threadIdx.x & 7) * 4;
    const float4 v = *(const float4*)(W + (size_t)(r0 + trd) * C + c0 + tc4);
    tl[trd][tc4 + 0] = v.x; tl[trd][tc4 + 1] = v.y;
    tl[trd][tc4 + 2] = v.z; tl[trd][tc4 + 3] = v.w;
    __syncthreads();
    u16x4 o;
#pragma unroll
    for (int q = 0; q < 4; ++q) o[q] = f2bf(tl[tc4 + q][trd]);
    *(u16x4*)(WT + (size_t)(c0 + trd) * R + r0 + tc4) = o;
}

// ---------------- pack qkv biases -> [NLAY][2304] ----------------
__global__ __launch_bounds__(256) void pack_bias_k(
    const float* __restrict__ bq, const float* __restrict__ bk,
    const float* __restrict__ bv, float* __restrict__ out)
{
    int l = blockIdx.x / 3, r = blockIdx.x - (blockIdx.x / 3) * 3;
    const float* src = r == 0 ? bq : r == 1 ? bk : bv;
#pragma unroll
    for (int j = 0; j < 3; ++j) {
        int d = threadIdx.x + 256 * j;
        out[(size_t)l * QKVN + r * H + d] = src[(size_t)l * H + d];
    }
}

// ---------------- embeddings + LN -> bf16 h; 4 tokens/block, 1 wave/token ----------------
__global__ __launch_bounds__(256) void embed_ln_k(
    const int* __restrict__ ids, const int* __restrict__ tts,
    const float* __restrict__ wemb, const float* __restrict__ pemb,
    const float* __restrict__ temb, const float* __restrict__ g,
    const float* __restrict__ bp, ushortT* __restrict__ hb)
{
    const int tok = blockIdx.x * 4 + (threadIdx.x >> 6);
    const int lane = threadIdx.x & 63;
    const int d0 = lane * 12;
    const int spos = tok & (S - 1);
    const int id = ids[tok], tt = tts[tok];
    const float* wr = wemb + (size_t)id * H + d0;
    const float* pr = pemb + (size_t)spos * H + d0;
    const float* tr = temb + (size_t)tt * H + d0;
    float x[12]; float s = 0.f, ss = 0.f;
#pragma unroll
    for (int j = 0; j < 3; ++j) {
        float4 a = *(const float4*)(wr + j * 4);
        float4 b = *(const float4*)(pr + j * 4);
        float4 c = *(const float4*)(tr + j * 4);
        float v0 = a.x + b.x + c.x, v1 = a.y + b.y + c.y;
        float v2 = a.z + b.z + c.z, v3 = a.w + b.w + c.w;
        x[j*4+0] = v0; x[j*4+1] = v1; x[j*4+2] = v2; x[j*4+3] = v3;
        s += v0 + v1 + v2 + v3;
        ss += v0*v0 + v1*v1 + v2*v2 + v3*v3;
    }
#pragma unroll
    for (int m = 32; m; m >>= 1) { s += __shfl_xor(s, m); ss += __shfl_xor(ss, m); }
    float mu = s * (1.f / H);
    float var = ss * (1.f / H) - mu * mu;
    float rs = rsqrtf(var + 1e-12f);
#pragma unroll
    for (int j = 0; j < 3; ++j) {
        float4 gv = *(const float4*)(g + d0 + j * 4);
        float4 bv = *(const float4*)(bp + d0 + j * 4);
        u16x4 o;
        o[0] = f2bf((x[j*4+0] - mu) * rs * gv.x + bv.x);
        o[1] = f2bf((x[j*4+1] - mu) * rs * gv.y + bv.y);
        o[2] = f2bf((x[j*4+2] - mu) * rs * gv.z + bv.z);
        o[3] = f2bf((x[j*4+3] - mu) * rs * gv.w + bv.w);
        *(u16x4*)(hb + (size_t)tok * H + d0 + j * 4) = o;
    }
}

// ---------------- bf16 residual add + LN, in place on hb; 4 tokens/block ----------------
__global__ __launch_bounds__(256) void add_ln_k(
    ushortT* __restrict__ hb, const ushortT* __restrict__ add,
    const float* __restrict__ g, const float* __restrict__ bp)
{
    const int tok = blockIdx.x * 4 + (threadIdx.x >> 6);
    const int lane = threadIdx.x & 63;
    const int d0 = lane * 12;
    const size_t base = (size_t)tok * H + d0;
    float x[12]; float s = 0.f, ss = 0.f;
#pragma unroll
    for (int j = 0; j < 3; ++j) {
        u16x4 hv = *(const u16x4*)(hb + base + j * 4);
        u16x4 av = *(const u16x4*)(add + base + j * 4);
#pragma unroll
        for (int q = 0; q < 4; ++q) {
            float v = bf2f(hv[q]) + bf2f(av[q]);
            x[j*4+q] = v; s += v; ss += v * v;
        }
    }
#pragma unroll
    for (int m = 32; m; m >>= 1) { s += __shfl_xor(s, m); ss += __shfl_xor(ss, m); }
    float mu = s * (1.f / H);
    float var = ss * (1.f / H) - mu * mu;
    float rs = rsqrtf(var + 1e-12f);
#pragma unroll
    for (int j = 0; j < 3; ++j) {
        float4 gv = *(const float4*)(g + d0 + j * 4);
        float4 bv = *(const float4*)(bp + d0 + j * 4);
        u16x4 o;
        o[0] = f2bf((x[j*4+0] - mu) * rs * gv.x + bv.x);
        o[1] = f2bf((x[j*4+1] - mu) * rs * gv.y + bv.y);
        o[2] = f2bf((x[j*4+2] - mu) * rs * gv.z + bv.z);
        o[3] = f2bf((x[j*4+3] - mu) * rs * gv.w + bv.w);
        *(u16x4*)(hb + base + j * 4) = o;
    }
}

// ---------------- logits + log_softmax over 9 labels (bf16 h, f32 math) ----------------
__global__ __launch_bounds__(256) void logits_k(
    const ushortT* __restrict__ hb, const float* __restrict__ fcw,
    float* __restrict__ em)
{
    int tok = blockIdx.x, tid = threadIdx.x;
    float p[LBL];
#pragma unroll
    for (int l = 0; l < LBL; ++l) p[l] = 0.f;
    const ushortT* hr = hb + (size_t)tok * H;
#pragma unroll
    for (int j = 0; j < 3; ++j) {
        int d = tid + 256 * j;
        float hv = bf2f(hr[d]);
        const float* fr = fcw + (size_t)d * LBL;
#pragma unroll
        for (int l = 0; l < LBL; ++l) p[l] = fmaf(hv, fr[l], p[l]);
    }
    __shared__ float ls[4][LBL];
    __shared__ float lg[LBL];
    __shared__ float lse;
#pragma unroll
    for (int l = 0; l < LBL; ++l) {
        float v = p[l];
#pragma unroll
        for (int m = 32; m; m >>= 1) v += __shfl_xor(v, m);
        if ((tid & 63) == 0) ls[tid >> 6][l] = v;
    }
    __syncthreads();
    if (tid < LBL) lg[tid] = ls[0][tid] + ls[1][tid] + ls[2][tid] + ls[3][tid];
    __syncthreads();
    if (tid == 0) {
        float mx = lg[0];
#pragma unroll
        for (int j = 1; j < LBL; ++j) mx = fmaxf(mx, lg[j]);
        float sm = 0.f;
#pragma unroll
        for (int j = 0; j < LBL; ++j) sm += expf(lg[j] - mx);
        lse = mx + logf(sm);
    }
    __syncthreads();
    if (tid < LBL) em[(size_t)tok * LBL + tid] = lg[tid] - lse;
}

// ---------------- CRF: one wave per batch elem, base-2 fast recursion ----------------
__global__ __launch_bounds__(64) void crf_k(
    const float* __restrict__ em, const int* __restrict__ tags,
    const int* __restrict__ mask, const float* __restrict__ sp,
    const float* __restrict__ ep, const float* __restrict__ trans,
    float* __restrict__ partial)
{
    constexpr float LOG2E = 1.4426950408889634f;
    constexpr float LN2   = 0.6931471805599453f;
    int b = blockIdx.x, t = threadIdx.x;
    __shared__ float eml[S * LBL];     // emissions * log2(e)
    __shared__ int mkl[S];
    const float* emb = em + (size_t)b * S * LBL;
    const int* tg = tags + (size_t)b * S;
    const int* mk = mask + (size_t)b * S;

    for (int i = t * 4; i < S * LBL; i += 256) {
        float4 v = *(const float4*)&emb[i];
        v.x *= LOG2E; v.y *= LOG2E; v.z *= LOG2E; v.w *= LOG2E;
        *(float4*)&eml[i] = v;
    }
    *(i32x4*)&mkl[t * 4] = *(const i32x4*)&mk[t * 4];

    int cnt = 0; float ns = 0.f;
    for (int i = t; i < S; i += 64) {
        int m = mk[i];
        cnt += (m != 0);
        if (i >= 1 && m)
            ns += trans[tg[i - 1] * LBL + tg[i]] + emb[(size_t)i * LBL + tg[i]];
    }
#pragma unroll
    for (int m = 32; m; m >>= 1) { cnt += __shfl_xor(cnt, m); ns += __shfl_xor(ns, m); }
    float num = ns + sp[tg[0]] + emb[tg[0]] + ep[tg[cnt - 1]];

    int tt = t < LBL ? t : 0;
    float trc2[LBL];
#pragma unroll
    for (int i = 0; i < LBL; ++i) trc2[i] = trans[i * LBL + tt] * LOG2E;

    __syncthreads();

    float alpha2 = (t < LBL) ? sp[t] * LOG2E + eml[t] : -1e30f;
    for (int step = 1; step < S; ++step) {
        float av[LBL];
#pragma unroll
        for (int i = 0; i < LBL; ++i) av[i] = __shfl(alpha2, i) + trc2[i];
        float mx = av[0];
#pragma unroll
        for (int i = 1; i < LBL; ++i) mx = fmaxf(mx, av[i]);
        float sm = 0.f;
#pragma unroll
        for (int i = 0; i < LBL; ++i) sm += exp2i(av[i] - mx);
        float na = mx + log2i(sm) + eml[step * LBL + tt];
        alpha2 = (mkl[step] && t < LBL) ? na : alpha2;
    }
    float z = (t < LBL) ? alpha2 + ep[t] * LOG2E : -1e30f;
    float mx = z;
#pragma unroll
    for (int m = 8; m; m >>= 1) mx = fmaxf(mx, __shfl_xor(mx, m));
    float sm = exp2i(z - mx);
#pragma unroll
    for (int m = 8; m; m >>= 1) sm += __shfl_xor(sm, m);
    if (t == 0) partial[b] = (mx + log2i(sm)) * LN2 - num;
}

__global__ void finalize_k(const float* __restrict__ partial, float* __restrict__ out) {
    float s = 0.f;
    for (int i = 0; i < BATCH; ++i) s += partial[i];
    out[0] = s;
}

__global__ void sentinel_k(float* out) { out[0] = -12345.0f; }

extern "C" void kernel_launch(void* const* d_in, const int* in_sizes, int n_in,
                              void* d_out, int out_size, void* d_ws, size_t ws_size,
                              hipStream_t stream) {
    (void)in_sizes; (void)n_in; (void)out_size;
    const int* token_ids  = (const int*)d_in[0];
    const int* token_type = (const int*)d_in[1];
    const int* amask      = (const int*)d_in[2];
    const int* y          = (const int*)d_in[3];
    const float* wemb = (const float*)d_in[4];
    const float* pemb = (const float*)d_in[5];
    const float* temb = (const float*)d_in[6];
    const float* eg   = (const float*)d_in[7];
    const float* eb   = (const float*)d_in[8];
    const float* Wq = (const float*)d_in[9];
    const float* bq = (const float*)d_in[10];
    const float* Wk = (const float*)d_in[11];
    const float* bk = (const float*)d_in[12];
    const float* Wv = (const float*)d_in[13];
    const float* bv = (const float*)d_in[14];
    const float* Wo = (const float*)d_in[15];
    const float* bo = (const float*)d_in[16];
    const float* ln1g = (const float*)d_in[17];
    const float* ln1b = (const float*)d_in[18];
    const float* W1 = (const float*)d_in[19];
    const float* b1 = (const float*)d_in[20];
    const float* W2 = (const float*)d_in[21];
    const float* b2 = (const float*)d_in[22];
    const float* ln2g = (const float*)d_in[23];
    const float* ln2b = (const float*)d_in[24];
    const float* fcw = (const float*)d_in[25];
    const float* crf_s = (const float*)d_in[26];
    const float* crf_e = (const float*)d_in[27];
    const float* crf_t = (const float*)d_in[28];

    if (ws_size < WS_FLOATS * sizeof(float)) {
        sentinel_k<<<1, 1, 0, stream>>>((float*)d_out);
        return;
    }

    float* ws = (float*)d_ws;
    ushortT* hb   = (ushortT*)(ws + HB_OFF);
    ushortT* qb   = (ushortT*)(ws + QB_OFF);   // q base; k = +TOKENS*H; vt = +2*TOKENS*H
    ushortT* kb   = (ushortT*)(ws + KB_OFF);
    ushortT* vt   = (ushortT*)(ws + VT_OFF);
    ushortT* big  = (ushortT*)(ws + BIG_OFF);
    ushortT* wtq  = (ushortT*)(ws + WTQ_OFF);  // [2304][768]
    ushortT* wto  = (ushortT*)(ws + WTO_OFF);
    ushortT* wt1  = (ushortT*)(ws + WT1_OFF);
    ushortT* wt2  = (ushortT*)(ws + WT2_OFF);
    float*   embuf = ws + EM_OFF;
    float*   part  = ws + PART_OFF;
    float*   bqkv  = ws + BQKV_OFF;

    pack_bias_k<<<NLAY * 3, 256, 0, stream>>>(bq, bk, bv, bqkv);
    embed_ln_k<<<TOKENS / 4, 256, 0, stream>>>(token_ids, token_type, wemb, pemb,
                                               temb, eg, eb, hb);

    constexpr long long HH = (long long)H * H;
    constexpr long long HF = (long long)H * FF;
    constexpr long long TOKH = (long long)S * H;        // 196608
    constexpr long long ATT_B = (long long)NHD * S * S; // 786432
    constexpr long long ATT_H = (long long)S * S;       // 65536
    constexpr long long VT_B = (long long)NHD * DH * S; // 196608
    constexpr long long VT_H = (long long)DH * S;       // 16384

    dim3 gQKV(QKVN / 128, TOKENS / 128, 1);       // 18 x 64 = 1152 (%8==0)
    dim3 gProj(H / 128, TOKENS / 128, 1);         // 6 x 64 = 384
    dim3 gFF1(FF / 128, TOKENS / 128, 1);         // 24 x 64 = 1536
    dim3 gScores(1, S / 64, BATCH * NHD);         // (N/256, M/64, 384) = 1x4x384
    dim3 gPV(1, 1, BATCH * NHD);                  // 256x64 tile covers head

    for (int l = 0; l < NLAY; ++l) {
        transpose_all_k<<<6912, 256, 0, stream>>>(
            Wq + l * HH, Wk + l * HH, Wv + l * HH, Wo + l * HH,
            W1 + l * HF, W2 + l * HF, wtq, wto, wt1, wt2);

        // fused q,k,v projections (3-buffer pipelined 128^2 with routing epilogue)
        gemm_mfma<2,2,5><<<gQKV, 256, 0, stream>>>(
            hb, H, 0, 0, wtq, H, 0, 0, bqkv + (size_t)l * QKVN,
            qb, H, 0, 0, H, 1);

        // probs = softmax(mask(q @ k^T)) per (b,h), fused epilogue -> bf16
        gemm_mfma<1,4,6><<<gScores, 256, 0, stream>>>(
            qb, H, TOKH, DH, kb, H, TOKH, DH, (const float*)amask,
            big, S, ATT_B, ATT_H, DH, NHD);

        // ctx = probs @ v  (per b,h) -> qb as [B,S,NH,DH] bf16
        gemm_mfma<4,1,4><<<gPV, 256, 0, stream>>>(
            big, S, ATT_B, ATT_H, vt, S, VT_B, VT_H, nullptr,
            qb, H, TOKH, DH, S, NHD);

        // attention output projection -> kb (bf16)
        gemm_mfma<2,2,0><<<gProj, 256, 0, stream>>>(
            qb, H, 0, 0, wto, H, 0, 0, bo + l * H, kb, H, 0, 0, H, 1);

        add_ln_k<<<TOKENS / 4, 256, 0, stream>>>(hb, kb, ln1g + l * H, ln1b + l * H);

        // ff1 = gelu(h @ W1 + b1) -> big bf16
        gemm_mfma<2,2,1><<<gFF1, 256, 0, stream>>>(
            hb, H, 0, 0, wt1, H, 0, 0, b1 + (long long)l * FF, big, FF, 0, 0, H, 1);

        // ff2 -> qb (bf16)
        gemm_mfma<2,2,0><<<gProj, 256, 0, stream>>>(
            big, FF, 0, 0, wt2, FF, 0, 0, b2 + l * H, qb, H, 0, 0, FF, 1);

        add_ln_k<<<TOKENS / 4, 256, 0, stream>>>(hb, qb, ln2g + l * H, ln2b + l * H);
    }

    logits_k<<<TOKENS, 256, 0, stream>>>(hb, fcw, embuf);
    crf_k<<<BATCH, 64, 0, stream>>>(embuf, y, amask, crf_s, crf_e, crf_t, part);
    finalize_k<<<1, 1, 0, stream>>>(part, (float*)d_out);
}